// Round 7
// baseline (300.394 us; speedup 1.0000x reference)
//
#include <hip/hip_runtime.h>
#include <cstdint>

#define HH 512
#define WW 512
#define TX 28          // output tile width; 19 tiles cover 512 (last partial)
// grid = 16 * 64 * 19 = 19456 blocks

typedef __attribute__((ext_vector_type(8)))  short    short8;
typedef __attribute__((ext_vector_type(16))) float    f32x16;
typedef __attribute__((ext_vector_type(2)))  unsigned u32x2;
typedef long long lng;

union FragU { uint4 u; short8 s; };
union U4L   { uint4 u; lng l[2]; };
union B8U   { u32x2 u2[2]; short8 s; };
union BL    { unsigned w[2]; lng l; };

// ---- LDS layout (bytes) ----
// fp8 act slot = 12B (ci0-3 @0, ci4-7 @4, ci8-11 @8)
#define L1F_O  0        // 12 rows x 32 px x 12B
#define L1W_O  4608
#define L1RST  384
#define MOS_O  9216     // 14 rows x 34 px x 8B bf16 (dead after L1 pass)
#define MOSR   272
#define L2F_O  9216     // aliases mosaic; 10 x 34-slot rows x 12B (30 valid px)
#define L2W_O  13296
#define L2RST  408
#define RELAY_O 0       // aliases dead L1 during L3 phase; 128 slots x 48B
#define SMEMB  17376

__device__ __forceinline__ unsigned cvtpk(float a, float b) {
  unsigned r;
  asm("v_cvt_pk_bf16_f32 %0, %1, %2" : "=v"(r) : "v"(a), "v"(b));
  return r;
}
__device__ __forceinline__ unsigned rpk8(float a, float b, float c, float d, bool im) {
  int r = __builtin_amdgcn_cvt_pk_fp8_f32(fmaxf(a, 0.f), fmaxf(b, 0.f), 0, false);
  r = __builtin_amdgcn_cvt_pk_fp8_f32(fmaxf(c, 0.f), fmaxf(d, 0.f), r, true);
  return im ? (unsigned)r : 0u;
}
__device__ __forceinline__ unsigned short f2bf(float f) {
  union { float f; unsigned u; } v; v.f = f;
  unsigned r = v.u + 0x7fffu + ((v.u >> 16) & 1u);
  return (unsigned short)(r >> 16);
}
__device__ __forceinline__ float bf2f(unsigned short b) {
  union { unsigned u; float f; } v; v.u = ((unsigned)b) << 16;
  return v.f;
}
__device__ __forceinline__ float lo16(unsigned u) {
  union { unsigned v; float f; } x; x.v = u << 16; return x.f;
}
__device__ __forceinline__ float hi16(unsigned u) {
  union { unsigned v; float f; } x; x.v = u & 0xffff0000u; return x.f;
}
__device__ __forceinline__ lng rd8(const char* p) {
  BL t;
  t.w[0] = *(const unsigned*)p;
  t.w[1] = *(const unsigned*)(p + 4);
  return t.l;
}

// ---------------- weight fragment packer ----------------
// f 0-2: L1 merged bf16 (ky=f), rows 0-11 = fw0 co, 12-23 = ww0 co;
//        slot sq = 2h + e/4 -> kx = sq (sq==3 zero). 16B/lane.
// f 3-9: L2 F j / 10-16: L2 W j / 17-23: L3 F j / 24-30: L3 W j — fp8, 8B/lane.
// L3 W weights (f 24-30) pre-scaled by 1/ln2 so softmax uses exp2 directly.
// fp8 quads (27, quad q covers kappa 4q..4q+3; kappa = tap*12+ci;
// off(q) = (q/9)*RST + 4*(q%9)). (j,h) -> byte-adjacent quad pair:
//   j0:(0,1)/(2,3) j1:(4,5)/(6,7) j2:(9,10)/(11,12) j3:(13,14)/(15,16)
//   j4:(18,19)/(20,21) j5:(22,23)/(24,25) j6:(8,17)split / (26,pad)
__global__ void wt_kernel(const float* __restrict__ fw0, const float* __restrict__ fw1,
                          const float* __restrict__ fw2, const float* __restrict__ ww0,
                          const float* __restrict__ ww1, const float* __restrict__ ww2,
                          uint4* __restrict__ wsf) {
  int t = blockIdx.x * 256 + threadIdx.x;
  if (t >= 31 * 64) return;
  int f = t >> 6, lane = t & 63;
  int h = (lane >> 5) & 1, m = lane & 31;
  uint4 o = make_uint4(0, 0, 0, 0);
  if (f < 3) {
    unsigned short v[8];
#pragma unroll
    for (int e = 0; e < 8; ++e) {
      int sq = 2 * h + (e >> 2);
      int c4 = e & 3;
      float w = 0.f;
      if (sq < 3 && m < 24) {
        w = (m < 12) ? fw0[(m * 4 + c4) * 9 + f * 3 + sq]
                     : ww0[((m - 12) * 4 + c4) * 9 + f * 3 + sq];
      }
      v[e] = f2bf(w);
    }
    o.x = (unsigned)v[0] | ((unsigned)v[1] << 16);
    o.y = (unsigned)v[2] | ((unsigned)v[3] << 16);
    o.z = (unsigned)v[4] | ((unsigned)v[5] << 16);
    o.w = (unsigned)v[6] | ((unsigned)v[7] << 16);
  } else {
    const int PR[7][2][2] = {
      {{0, 1}, {2, 3}}, {{4, 5}, {6, 7}}, {{9, 10}, {11, 12}},
      {{13, 14}, {15, 16}}, {{18, 19}, {20, 21}}, {{22, 23}, {24, 25}},
      {{8, 17}, {26, -1}}};
    int fi = f - 3, layer = fi / 14, path = (fi % 14) / 7, j = fi % 7;
    const float* src = layer ? (path ? ww2 : fw2) : (path ? ww1 : fw1);
    const float scale = (layer == 1 && path == 1) ? 1.44269504f : 1.0f;
    float wv[8];
#pragma unroll
    for (int p = 0; p < 8; ++p) {
      int q = PR[j][h][p >> 2];
      int c = p & 3;
      float w = 0.f;
      if (q >= 0 && m < 12) {
        int kap = 4 * q + c;
        int tap = kap / 12, ci = kap % 12;
        w = src[(m * 12 + ci) * 9 + tap] * scale;
      }
      wv[p] = w;
    }
    int x = __builtin_amdgcn_cvt_pk_fp8_f32(wv[0], wv[1], 0, false);
    x = __builtin_amdgcn_cvt_pk_fp8_f32(wv[2], wv[3], x, true);
    int y = __builtin_amdgcn_cvt_pk_fp8_f32(wv[4], wv[5], 0, false);
    y = __builtin_amdgcn_cvt_pk_fp8_f32(wv[6], wv[7], y, true);
    o.x = (unsigned)x; o.y = (unsigned)y;
  }
  wsf[t] = o;
}

// dual fp8 12->12 conv group: 7 MFMAs each on F and W chains.
// Ph = base + 8h; Pa = base + (h?2RST:0); Pb = base + (h?2RST:RST).
template<int RST, int WIN>
__device__ __forceinline__ void conv12f8(const lng* aF, const lng* aW,
                                         const char* Ph, const char* Pa, const char* Pb,
                                         int imm, f32x16& cF, f32x16& cW) {
  const int IM[6] = {0, 16, RST, RST + 16, 2 * RST, 2 * RST + 16};
#pragma unroll
  for (int j = 0; j < 6; ++j) {
    lng bF = rd8(Ph + imm + IM[j]);
    lng bW = rd8(Ph + imm + IM[j] + WIN);
    cF = __builtin_amdgcn_mfma_f32_32x32x16_fp8_fp8(aF[j], bF, cF, 0, 0, 0);
    cW = __builtin_amdgcn_mfma_f32_32x32x16_fp8_fp8(aW[j], bW, cW, 0, 0, 0);
  }
  {
    BL bF, bW;
    bF.w[0] = *(const unsigned*)(Pa + imm + 32);
    bF.w[1] = *(const unsigned*)(Pb + imm + 32);
    bW.w[0] = *(const unsigned*)(Pa + imm + 32 + WIN);
    bW.w[1] = *(const unsigned*)(Pb + imm + 32 + WIN);
    cF = __builtin_amdgcn_mfma_f32_32x32x16_fp8_fp8(aF[6], bF.l, cF, 0, 0, 0);
    cW = __builtin_amdgcn_mfma_f32_32x32x16_fp8_fp8(aW[6], bW.l, cW, 0, 0, 0);
  }
}

// store M=12 C/D as fp8 (h0 regs0-3->ci0-3 @+0, regs4-7->ci8-11 @+8; h1 regs0-3->ci4-7 @+4)
// pO already includes +4h.
template<int WOUT>
__device__ __forceinline__ void store12f8(char* pO, int imm, const f32x16& cF,
                                          const f32x16& cW, bool im, int h) {
  *(unsigned*)(pO + imm) = rpk8(cF[0], cF[1], cF[2], cF[3], im);
  *(unsigned*)(pO + imm + WOUT) = rpk8(cW[0], cW[1], cW[2], cW[3], im);
  if (h == 0) {
    *(unsigned*)(pO + imm + 8) = rpk8(cF[4], cF[5], cF[6], cF[7], im);
    *(unsigned*)(pO + imm + WOUT + 8) = rpk8(cW[4], cW[5], cW[6], cW[7], im);
  }
}

// ---------------- fused 3-layer x 2-path conv via MFMA + in-reg softmax green ----------------
__global__ __launch_bounds__(256, 8)
void green_kernel(const float* __restrict__ mosaic, const uint4* __restrict__ wsf,
                  unsigned short* __restrict__ green) {
  __shared__ __align__(16) char s[SMEMB];
  const int tid = threadIdx.x;
  const int lane = tid & 63;
  const int wv = __builtin_amdgcn_readfirstlane(tid >> 6);
  const int h = (lane >> 5) & 1, ln = lane & 31;
  const int ln8 = ln * 8, ln12 = ln * 12;
  const int bid = blockIdx.x;
  const int bx = bid % 19;
  const int t19 = bid / 19;
  const int by = t19 & 63, b = t19 >> 6;
  const int X0 = bx * TX, Y0 = by * 8;

  // ---- stage 0: mosaic tile 14x34, 4ch bf16-packed (8B/px), zero outside image ----
  {
    const float* mb = mosaic + (size_t)b * 4 * HH * WW;
    for (int p = tid; p < 14 * 34; p += 256) {
      int row = p / 34, col = p - row * 34;
      int gy = Y0 + row - 3, gx = X0 + col - 3;
      float c0 = 0.f, c1 = 0.f, c2 = 0.f, c3 = 0.f;
      if ((unsigned)gy < HH && (unsigned)gx < WW) {
        const float* mp = mb + (size_t)gy * WW + gx;
        c0 = mp[0]; c1 = mp[HH * WW]; c2 = mp[2 * HH * WW]; c3 = mp[3 * HH * WW];
      }
      u32x2 w = { cvtpk(c0, c1), cvtpk(c2, c3) };
      *(u32x2*)(s + MOS_O + row * MOSR + col * 8) = w;
    }
  }
  __syncthreads();

  // ---- L1: 4->12 both paths in one bf16 MFMA (M: F 0-11, W 12-23), out 12x32 fp8 ----
  {
    FragU a3[3];
#pragma unroll
    for (int q = 0; q < 3; ++q) a3[q].u = wsf[q * 64 + lane];
    const char* pLo = s + MOS_O + 3 * wv * MOSR + ln8 + 16 * h;  // sem kx = 2h
    const char* pHi = s + MOS_O + 3 * wv * MOSR + ln8 + 8;       // sem kx=1 (h0); pad (h1)
    char* base = s + 3 * wv * L1RST + ln12;
    char* pA = base + L1F_O + 4 * h;                 // F d0 (h0) / F d1 (h1)
    char* pB = h ? base + L1W_O : base + L1F_O + 8;  // W d0 (h1) / F d2 (h0)
    char* pC = base + L1W_O + (h ? 8 : 4);           // W d2 (h1) / W d1 (h0)
    const bool ckx = (unsigned)(X0 + ln - 2) < WW;
#pragma unroll
    for (int r = 0; r < 3; ++r) {
      const int ly = 3 * wv + r;
      const bool rowok = (unsigned)(Y0 + ly - 2) < HH;
      f32x16 c = {};
#pragma unroll
      for (int ky = 0; ky < 3; ++ky) {
        B8U bu;
        bu.u2[0] = *(const u32x2*)(pLo + (r + ky) * MOSR);
        bu.u2[1] = *(const u32x2*)(pHi + (r + ky) * MOSR);
        c = __builtin_amdgcn_mfma_f32_32x32x16_bf16(a3[ky].s, bu.s, c, 0, 0, 0);
      }
      const bool im = rowok && ckx;
      *(unsigned*)(pA + r * L1RST) = rpk8(c[0], c[1], c[2], c[3], im);
      *(unsigned*)(pB + r * L1RST) = rpk8(c[4], c[5], c[6], c[7], im);
      *(unsigned*)(pC + r * L1RST) = rpk8(c[8], c[9], c[10], c[11], im);
    }
  }
  __syncthreads();

  // ---- L2: 12->12 both chains fp8, out 10x30 (cols 30,31 garbage, never read) ----
  {
    lng aF[7], aW[7];
#pragma unroll
    for (int j = 0; j < 7; ++j) {
      U4L u; u.u = wsf[(3 + j) * 64 + lane];  aF[j] = u.l[0];
      U4L v; v.u = wsf[(10 + j) * 64 + lane]; aW[j] = v.l[0];
    }
    const char* base = s + L1F_O + wv * L1RST + ln12;
    const char* Ph = base + 8 * h;
    const char* Pa = base + (h ? 2 * L1RST : 0);
    const char* Pb = base + (h ? 2 * L1RST : L1RST);
    char* bO0 = s + L2F_O + wv * L2RST + ln12 + 4 * h;
    const bool ckx = (unsigned)(X0 + ln - 1) < WW;
#pragma unroll
    for (int i = 0; i < 3; ++i) {
      const int ly = wv + 4 * i;
      if (ly < 10) {
        const bool rowok = (unsigned)(Y0 + ly - 1) < HH;
        f32x16 cF = {}, cW = {};
        conv12f8<L1RST, 4608>(aF, aW, Ph, Pa, Pb, i * 4 * L1RST, cF, cW);
        store12f8<4080>(bO0, i * 4 * L2RST, cF, cW, rowok && ckx, h);
      }
    }
  }
  __syncthreads();

  // ---- L3: 12->12 both chains fp8, in-register + relay softmax, out 8x28 ----
  {
    lng aF[7], aW[7];
#pragma unroll
    for (int j = 0; j < 7; ++j) {
      U4L u; u.u = wsf[(17 + j) * 64 + lane]; aF[j] = u.l[0];
      U4L v; v.u = wsf[(24 + j) * 64 + lane]; aW[j] = v.l[0];
    }
    const char* base = s + L2F_O + 2 * wv * L2RST + ln12;
    const char* Ph = base + 8 * h;
    const char* Pa = base + (h ? 2 * L2RST : 0);
    const char* Pb = base + (h ? 2 * L2RST : L2RST);
    char* slot = s + RELAY_O + (wv * 32 + ln) * 48;
#pragma unroll
    for (int r = 0; r < 2; ++r) {
      f32x16 cF = {}, cW = {};
      conv12f8<L2RST, 4080>(aF, aW, Ph, Pa, Pb, r * L2RST, cF, cW);
      const int cidx = r;   // which half computes this call
      if (cidx == 0) {
        if (h) {            // h1 sends its ci4-7 (F then W) as bf16
          uint4 pay;
          pay.x = cvtpk(fmaxf(cF[0], 0.f), fmaxf(cF[1], 0.f));
          pay.y = cvtpk(fmaxf(cF[2], 0.f), fmaxf(cF[3], 0.f));
          pay.z = cvtpk(fmaxf(cW[0], 0.f), fmaxf(cW[1], 0.f));
          pay.w = cvtpk(fmaxf(cW[2], 0.f), fmaxf(cW[3], 0.f));
          *(uint4*)slot = pay;
        }
      } else {
        if (!h) {           // h0 sends ci0-3 + ci8-11 (F then W)
          uint4 pa, pb;
          pa.x = cvtpk(fmaxf(cF[0], 0.f), fmaxf(cF[1], 0.f));
          pa.y = cvtpk(fmaxf(cF[2], 0.f), fmaxf(cF[3], 0.f));
          pa.z = cvtpk(fmaxf(cF[4], 0.f), fmaxf(cF[5], 0.f));
          pa.w = cvtpk(fmaxf(cF[6], 0.f), fmaxf(cF[7], 0.f));
          pb.x = cvtpk(fmaxf(cW[0], 0.f), fmaxf(cW[1], 0.f));
          pb.y = cvtpk(fmaxf(cW[2], 0.f), fmaxf(cW[3], 0.f));
          pb.z = cvtpk(fmaxf(cW[4], 0.f), fmaxf(cW[5], 0.f));
          pb.w = cvtpk(fmaxf(cW[6], 0.f), fmaxf(cW[7], 0.f));
          *(uint4*)slot = pa;
          *(uint4*)(slot + 16) = pb;
        }
      }
      asm volatile("s_waitcnt lgkmcnt(0)" ::: "memory");
      if (h == cidx) {
        float F[12], Wv[12];
        if (cidx == 0) {    // h0 computes: own ci0-3 & ci8-11; relayed ci4-7
          const uint4 pay = *(const uint4*)slot;
#pragma unroll
          for (int c2 = 0; c2 < 4; ++c2) {
            F[c2]      = fmaxf(cF[c2], 0.f);
            F[8 + c2]  = fmaxf(cF[4 + c2], 0.f);
            Wv[c2]     = fmaxf(cW[c2], 0.f);
            Wv[8 + c2] = fmaxf(cW[4 + c2], 0.f);
          }
          F[4] = lo16(pay.x);  F[5] = hi16(pay.x);
          F[6] = lo16(pay.y);  F[7] = hi16(pay.y);
          Wv[4] = lo16(pay.z); Wv[5] = hi16(pay.z);
          Wv[6] = lo16(pay.w); Wv[7] = hi16(pay.w);
        } else {            // h1 computes: own ci4-7; relayed ci0-3 & ci8-11
          const uint4 pa = *(const uint4*)slot;
          const uint4 pb = *(const uint4*)(slot + 16);
#pragma unroll
          for (int c2 = 0; c2 < 4; ++c2) {
            F[4 + c2]  = fmaxf(cF[c2], 0.f);
            Wv[4 + c2] = fmaxf(cW[c2], 0.f);
          }
          F[0] = lo16(pa.x);   F[1] = hi16(pa.x);
          F[2] = lo16(pa.y);   F[3] = hi16(pa.y);
          F[8] = lo16(pa.z);   F[9] = hi16(pa.z);
          F[10] = lo16(pa.w);  F[11] = hi16(pa.w);
          Wv[0] = lo16(pb.x);  Wv[1] = hi16(pb.x);
          Wv[2] = lo16(pb.y);  Wv[3] = hi16(pb.y);
          Wv[8] = lo16(pb.z);  Wv[9] = hi16(pb.z);
          Wv[10] = lo16(pb.w); Wv[11] = hi16(pb.w);
        }
        // W logits are pre-scaled by 1/ln2 -> exp2 is exact softmax
        float m = 0.f;
#pragma unroll
        for (int c2 = 0; c2 < 12; ++c2) m = fmaxf(m, Wv[c2]);
        float sum = 0.f, s0 = 0.f, s1 = 0.f;
#pragma unroll
        for (int c2 = 0; c2 < 12; ++c2) {
          const float e = exp2f(Wv[c2] - m);
          sum += e;
          if (c2 < 6) s0 = fmaf(F[c2], e, s0);
          else        s1 = fmaf(F[c2], e, s1);
        }
        const float inv = 1.f / sum;
        const unsigned pg = cvtpk(s0 * inv, s1 * inv);
        const int gy = Y0 + 2 * wv + r;
        const int gx = X0 + ln;
        if (ln < TX && (unsigned)gx < WW) {
          green[((b * 2 + 0) * HH + gy) * WW + gx] = (unsigned short)pg;
          green[((b * 2 + 1) * HH + gy) * WW + gx] = (unsigned short)(pg >> 16);
        }
      }
    }
  }
}

// ---------------- chroma conv 2->6 + pixel-shuffle assembly ----------------
__global__ __launch_bounds__(256)
void assemble_kernel(const float* __restrict__ mosaic, const unsigned short* __restrict__ green,
                     const float* __restrict__ cw0, float* __restrict__ out) {
  const int t = blockIdx.x * 256 + threadIdx.x;
  const int x = t & (WW - 1);
  const int y = (t >> 9) & (HH - 1);
  const int b = t >> 18;

  const int p = y * WW + x;
  const float* __restrict__ mb = mosaic + (size_t)b * 4 * HH * WW;
  const unsigned short* __restrict__ gb = green + (size_t)b * 2 * HH * WW;

  const float m0 = mb[p];
  const float m1 = mb[HH * WW + p];
  const float m2 = mb[2 * HH * WW + p];
  const float m3 = mb[3 * HH * WW + p];
  const float g0 = bf2f(gb[p]);
  const float g1 = bf2f(gb[HH * WW + p]);

  float cd[6] = {0.f, 0.f, 0.f, 0.f, 0.f, 0.f};
#pragma unroll
  for (int ky = 0; ky < 3; ++ky) {
#pragma unroll
    for (int kx = 0; kx < 3; ++kx) {
      const int yy = y + ky - 1, xx = x + kx - 1;
      float c0 = 0.f, c1 = 0.f;
      if ((unsigned)yy < HH && (unsigned)xx < WW) {
        const int q = yy * WW + xx;
        c0 = mb[HH * WW + q]     - bf2f(gb[q]);
        c1 = mb[2 * HH * WW + q] - bf2f(gb[HH * WW + q]);
      }
      const int k = ky * 3 + kx;
#pragma unroll
      for (int o = 0; o < 6; ++o) {
        cd[o] = fmaf(c0, cw0[(o * 2 + 0) * 9 + k], cd[o]);
        cd[o] = fmaf(c1, cw0[(o * 2 + 1) * 9 + k], cd[o]);
      }
    }
  }
  const float cp0 = cd[0] + m0;
  const float cp1 = cd[1] + g1;
  const float cp2 = cd[2] + m3;
  const float cp3 = cd[3] + m0;
  const float cp4 = cd[4] + g0;
  const float cp5 = cd[5] + m3;

  const int W2 = 2 * WW;
  const size_t plane = (size_t)(2 * HH) * W2;
  size_t base = ((size_t)(b * 3) * (2 * HH) + 2 * y) * W2 + 2 * x;
  *(float2*)(out + base)              = make_float2(cp0, m1);
  *(float2*)(out + base + W2)         = make_float2(cp1, cp2);
  *(float2*)(out + base + plane)      = make_float2(m0, g0);
  *(float2*)(out + base + plane + W2) = make_float2(g1, m3);
  *(float2*)(out + base + 2 * plane)      = make_float2(cp3, cp4);
  *(float2*)(out + base + 2 * plane + W2) = make_float2(m2, cp5);
}

extern "C" void kernel_launch(void* const* d_in, const int* in_sizes, int n_in,
                              void* d_out, int out_size, void* d_ws, size_t ws_size,
                              hipStream_t stream) {
  const float* mosaic = (const float*)d_in[0];
  const float* fw0 = (const float*)d_in[1];
  const float* fw1 = (const float*)d_in[2];
  const float* fw2 = (const float*)d_in[3];
  const float* ww0 = (const float*)d_in[4];
  const float* ww1 = (const float*)d_in[5];
  const float* ww2 = (const float*)d_in[6];
  const float* cw0 = (const float*)d_in[7];

  uint4* wsf = (uint4*)((char*)d_ws + 32768);
  unsigned short* green = (unsigned short*)((char*)d_ws + 67584);
  float* out = (float*)d_out;

  wt_kernel<<<8, 256, 0, stream>>>(fw0, fw1, fw2, ww0, ww1, ww2, wsf);
  green_kernel<<<16 * 64 * 19, 256, 0, stream>>>(mosaic, wsf, green);
  assemble_kernel<<<(16 * HH * WW) / 256, 256, 0, stream>>>(mosaic, green, cw0, out);
}

// Round 8
// 236.869 us; speedup vs baseline: 1.2682x; 1.2682x over previous
//
#include <hip/hip_runtime.h>
#include <cstdint>

#define HH 512
#define WW 512
#define TX 28          // output tile width; 19 tiles cover 512 (last partial)
// grid = 16 * 64 * 19 = 19456 blocks

typedef __attribute__((ext_vector_type(8)))  short    short8;
typedef __attribute__((ext_vector_type(16))) float    f32x16;
typedef __attribute__((ext_vector_type(2)))  unsigned u32x2;
typedef long long lng;

union FragU { uint4 u; short8 s; };
union U4L   { uint4 u; lng l[2]; };
union B8U   { u32x2 u2[2]; short8 s; };
union BL    { unsigned w[2]; lng l; };

// ---- LDS layout (bytes) ----
// fp8 act slot = 12B (ci0-3 @0, ci4-7 @4, ci8-11 @8)
#define L1F_O  0        // 12 rows x 32 px x 12B
#define L1W_O  4608
#define L1RST  384
#define MOS_O  9216     // 14 rows x 34 px x 8B bf16 (dead after L1 pass)
#define MOSR   272
#define L2F_O  9216     // aliases mosaic; 10 x 34-slot rows x 12B (30 valid px)
#define L2W_O  13296
#define L2RST  408
#define RELAY_O 0       // aliases dead L1 during L3 phase; 128 slots x 48B
#define SMEMB  17376

__device__ __forceinline__ unsigned cvtpk(float a, float b) {
  unsigned r;
  asm("v_cvt_pk_bf16_f32 %0, %1, %2" : "=v"(r) : "v"(a), "v"(b));
  return r;
}
__device__ __forceinline__ unsigned rpk8(float a, float b, float c, float d, bool im) {
  int r = __builtin_amdgcn_cvt_pk_fp8_f32(fmaxf(a, 0.f), fmaxf(b, 0.f), 0, false);
  r = __builtin_amdgcn_cvt_pk_fp8_f32(fmaxf(c, 0.f), fmaxf(d, 0.f), r, true);
  return im ? (unsigned)r : 0u;
}
__device__ __forceinline__ unsigned short f2bf(float f) {
  union { float f; unsigned u; } v; v.f = f;
  unsigned r = v.u + 0x7fffu + ((v.u >> 16) & 1u);
  return (unsigned short)(r >> 16);
}
__device__ __forceinline__ float bf2f(unsigned short b) {
  union { unsigned u; float f; } v; v.u = ((unsigned)b) << 16;
  return v.f;
}
__device__ __forceinline__ float lo16(unsigned u) {
  union { unsigned v; float f; } x; x.v = u << 16; return x.f;
}
__device__ __forceinline__ float hi16(unsigned u) {
  union { unsigned v; float f; } x; x.v = u & 0xffff0000u; return x.f;
}
__device__ __forceinline__ lng rd8(const char* p) {
  BL t;
  t.w[0] = *(const unsigned*)p;
  t.w[1] = *(const unsigned*)(p + 4);
  return t.l;
}

// ---------------- weight fragment packer ----------------
// f 0-2: L1 merged bf16 (ky=f), rows 0-11 = fw0 co, 12-23 = ww0 co;
//        slot sq = 2h + e/4 -> kx = sq (sq==3 zero). 16B/lane.
// f 3-9: L2 F j / 10-16: L2 W j / 17-23: L3 F j / 24-30: L3 W j — fp8, 8B/lane.
// L3 W weights (f 24-30) pre-scaled by 1/ln2 so softmax uses exp2 directly.
// fp8 quads (27, quad q covers kappa 4q..4q+3; kappa = tap*12+ci;
// off(q) = (q/9)*RST + 4*(q%9)). (j,h) -> byte-adjacent quad pair:
//   j0:(0,1)/(2,3) j1:(4,5)/(6,7) j2:(9,10)/(11,12) j3:(13,14)/(15,16)
//   j4:(18,19)/(20,21) j5:(22,23)/(24,25) j6:(8,17)split / (26,pad)
__global__ void wt_kernel(const float* __restrict__ fw0, const float* __restrict__ fw1,
                          const float* __restrict__ fw2, const float* __restrict__ ww0,
                          const float* __restrict__ ww1, const float* __restrict__ ww2,
                          uint4* __restrict__ wsf) {
  int t = blockIdx.x * 256 + threadIdx.x;
  if (t >= 31 * 64) return;
  int f = t >> 6, lane = t & 63;
  int h = (lane >> 5) & 1, m = lane & 31;
  uint4 o = make_uint4(0, 0, 0, 0);
  if (f < 3) {
    unsigned short v[8];
#pragma unroll
    for (int e = 0; e < 8; ++e) {
      int sq = 2 * h + (e >> 2);
      int c4 = e & 3;
      float w = 0.f;
      if (sq < 3 && m < 24) {
        w = (m < 12) ? fw0[(m * 4 + c4) * 9 + f * 3 + sq]
                     : ww0[((m - 12) * 4 + c4) * 9 + f * 3 + sq];
      }
      v[e] = f2bf(w);
    }
    o.x = (unsigned)v[0] | ((unsigned)v[1] << 16);
    o.y = (unsigned)v[2] | ((unsigned)v[3] << 16);
    o.z = (unsigned)v[4] | ((unsigned)v[5] << 16);
    o.w = (unsigned)v[6] | ((unsigned)v[7] << 16);
  } else {
    const int PR[7][2][2] = {
      {{0, 1}, {2, 3}}, {{4, 5}, {6, 7}}, {{9, 10}, {11, 12}},
      {{13, 14}, {15, 16}}, {{18, 19}, {20, 21}}, {{22, 23}, {24, 25}},
      {{8, 17}, {26, -1}}};
    int fi = f - 3, layer = fi / 14, path = (fi % 14) / 7, j = fi % 7;
    const float* src = layer ? (path ? ww2 : fw2) : (path ? ww1 : fw1);
    const float scale = (layer == 1 && path == 1) ? 1.44269504f : 1.0f;
    float wv[8];
#pragma unroll
    for (int p = 0; p < 8; ++p) {
      int q = PR[j][h][p >> 2];
      int c = p & 3;
      float w = 0.f;
      if (q >= 0 && m < 12) {
        int kap = 4 * q + c;
        int tap = kap / 12, ci = kap % 12;
        w = src[(m * 12 + ci) * 9 + tap] * scale;
      }
      wv[p] = w;
    }
    int x = __builtin_amdgcn_cvt_pk_fp8_f32(wv[0], wv[1], 0, false);
    x = __builtin_amdgcn_cvt_pk_fp8_f32(wv[2], wv[3], x, true);
    int y = __builtin_amdgcn_cvt_pk_fp8_f32(wv[4], wv[5], 0, false);
    y = __builtin_amdgcn_cvt_pk_fp8_f32(wv[6], wv[7], y, true);
    o.x = (unsigned)x; o.y = (unsigned)y;
  }
  wsf[t] = o;
}

// dual fp8 12->12 conv group: 7 MFMAs each on F and W chains.
// Ph = base + 8h; Pa = base + (h?2RST:0); Pb = base + (h?2RST:RST).
template<int RST, int WIN>
__device__ __forceinline__ void conv12f8(const lng* aF, const lng* aW,
                                         const char* Ph, const char* Pa, const char* Pb,
                                         int imm, f32x16& cF, f32x16& cW) {
  const int IM[6] = {0, 16, RST, RST + 16, 2 * RST, 2 * RST + 16};
#pragma unroll
  for (int j = 0; j < 6; ++j) {
    lng bF = rd8(Ph + imm + IM[j]);
    lng bW = rd8(Ph + imm + IM[j] + WIN);
    cF = __builtin_amdgcn_mfma_f32_32x32x16_fp8_fp8(aF[j], bF, cF, 0, 0, 0);
    cW = __builtin_amdgcn_mfma_f32_32x32x16_fp8_fp8(aW[j], bW, cW, 0, 0, 0);
  }
  {
    BL bF, bW;
    bF.w[0] = *(const unsigned*)(Pa + imm + 32);
    bF.w[1] = *(const unsigned*)(Pb + imm + 32);
    bW.w[0] = *(const unsigned*)(Pa + imm + 32 + WIN);
    bW.w[1] = *(const unsigned*)(Pb + imm + 32 + WIN);
    cF = __builtin_amdgcn_mfma_f32_32x32x16_fp8_fp8(aF[6], bF.l, cF, 0, 0, 0);
    cW = __builtin_amdgcn_mfma_f32_32x32x16_fp8_fp8(aW[6], bW.l, cW, 0, 0, 0);
  }
}

// store M=12 C/D as fp8 (h0 regs0-3->ci0-3 @+0, regs4-7->ci8-11 @+8; h1 regs0-3->ci4-7 @+4)
// pO already includes +4h.
template<int WOUT>
__device__ __forceinline__ void store12f8(char* pO, int imm, const f32x16& cF,
                                          const f32x16& cW, bool im, int h) {
  *(unsigned*)(pO + imm) = rpk8(cF[0], cF[1], cF[2], cF[3], im);
  *(unsigned*)(pO + imm + WOUT) = rpk8(cW[0], cW[1], cW[2], cW[3], im);
  if (h == 0) {
    *(unsigned*)(pO + imm + 8) = rpk8(cF[4], cF[5], cF[6], cF[7], im);
    *(unsigned*)(pO + imm + WOUT + 8) = rpk8(cW[4], cW[5], cW[6], cW[7], im);
  }
}

// ---------------- fused 3-layer x 2-path conv via MFMA + in-reg softmax green ----------------
// launch_bounds(256,6): VGPR cap ~85 (kernel needs ~52-60) -> NO scratch spill;
// 6 blocks/CU = 24 waves/CU. (256,8) capped VGPR at 64 -> spilled -> 379MB scratch writes.
__global__ __launch_bounds__(256, 6)
void green_kernel(const float* __restrict__ mosaic, const uint4* __restrict__ wsf,
                  unsigned short* __restrict__ green) {
  __shared__ __align__(16) char s[SMEMB];
  const int tid = threadIdx.x;
  const int lane = tid & 63;
  const int wv = __builtin_amdgcn_readfirstlane(tid >> 6);
  const int h = (lane >> 5) & 1, ln = lane & 31;
  const int ln8 = ln * 8, ln12 = ln * 12;
  const int bid = blockIdx.x;
  const int bx = bid % 19;
  const int t19 = bid / 19;
  const int by = t19 & 63, b = t19 >> 6;
  const int X0 = bx * TX, Y0 = by * 8;

  // ---- stage 0: mosaic tile 14x34, 4ch bf16-packed (8B/px), zero outside image ----
  {
    const float* mb = mosaic + (size_t)b * 4 * HH * WW;
    for (int p = tid; p < 14 * 34; p += 256) {
      int row = p / 34, col = p - row * 34;
      int gy = Y0 + row - 3, gx = X0 + col - 3;
      float c0 = 0.f, c1 = 0.f, c2 = 0.f, c3 = 0.f;
      if ((unsigned)gy < HH && (unsigned)gx < WW) {
        const float* mp = mb + (size_t)gy * WW + gx;
        c0 = mp[0]; c1 = mp[HH * WW]; c2 = mp[2 * HH * WW]; c3 = mp[3 * HH * WW];
      }
      u32x2 w = { cvtpk(c0, c1), cvtpk(c2, c3) };
      *(u32x2*)(s + MOS_O + row * MOSR + col * 8) = w;
    }
  }
  __syncthreads();

  // ---- L1: 4->12 both paths in one bf16 MFMA (M: F 0-11, W 12-23), out 12x32 fp8 ----
  {
    FragU a3[3];
#pragma unroll
    for (int q = 0; q < 3; ++q) a3[q].u = wsf[q * 64 + lane];
    const char* pLo = s + MOS_O + 3 * wv * MOSR + ln8 + 16 * h;  // sem kx = 2h
    const char* pHi = s + MOS_O + 3 * wv * MOSR + ln8 + 8;       // sem kx=1 (h0); pad (h1)
    char* base = s + 3 * wv * L1RST + ln12;
    char* pA = base + L1F_O + 4 * h;                 // F d0 (h0) / F d1 (h1)
    char* pB = h ? base + L1W_O : base + L1F_O + 8;  // W d0 (h1) / F d2 (h0)
    char* pC = base + L1W_O + (h ? 8 : 4);           // W d2 (h1) / W d1 (h0)
    const bool ckx = (unsigned)(X0 + ln - 2) < WW;
#pragma unroll
    for (int r = 0; r < 3; ++r) {
      const int ly = 3 * wv + r;
      const bool rowok = (unsigned)(Y0 + ly - 2) < HH;
      f32x16 c = {};
#pragma unroll
      for (int ky = 0; ky < 3; ++ky) {
        B8U bu;
        bu.u2[0] = *(const u32x2*)(pLo + (r + ky) * MOSR);
        bu.u2[1] = *(const u32x2*)(pHi + (r + ky) * MOSR);
        c = __builtin_amdgcn_mfma_f32_32x32x16_bf16(a3[ky].s, bu.s, c, 0, 0, 0);
      }
      const bool im = rowok && ckx;
      *(unsigned*)(pA + r * L1RST) = rpk8(c[0], c[1], c[2], c[3], im);
      *(unsigned*)(pB + r * L1RST) = rpk8(c[4], c[5], c[6], c[7], im);
      *(unsigned*)(pC + r * L1RST) = rpk8(c[8], c[9], c[10], c[11], im);
    }
  }
  __syncthreads();

  // ---- L2: 12->12 both chains fp8, out 10x30 (cols 30,31 garbage, never read) ----
  {
    lng aF[7], aW[7];
#pragma unroll
    for (int j = 0; j < 7; ++j) {
      U4L u; u.u = wsf[(3 + j) * 64 + lane];  aF[j] = u.l[0];
      U4L v; v.u = wsf[(10 + j) * 64 + lane]; aW[j] = v.l[0];
    }
    const char* base = s + L1F_O + wv * L1RST + ln12;
    const char* Ph = base + 8 * h;
    const char* Pa = base + (h ? 2 * L1RST : 0);
    const char* Pb = base + (h ? 2 * L1RST : L1RST);
    char* bO0 = s + L2F_O + wv * L2RST + ln12 + 4 * h;
    const bool ckx = (unsigned)(X0 + ln - 1) < WW;
#pragma unroll
    for (int i = 0; i < 3; ++i) {
      const int ly = wv + 4 * i;
      if (ly < 10) {
        const bool rowok = (unsigned)(Y0 + ly - 1) < HH;
        f32x16 cF = {}, cW = {};
        conv12f8<L1RST, 4608>(aF, aW, Ph, Pa, Pb, i * 4 * L1RST, cF, cW);
        store12f8<4080>(bO0, i * 4 * L2RST, cF, cW, rowok && ckx, h);
      }
    }
  }
  __syncthreads();

  // ---- L3: 12->12 both chains fp8, in-register + relay softmax, out 8x28 ----
  {
    lng aF[7], aW[7];
#pragma unroll
    for (int j = 0; j < 7; ++j) {
      U4L u; u.u = wsf[(17 + j) * 64 + lane]; aF[j] = u.l[0];
      U4L v; v.u = wsf[(24 + j) * 64 + lane]; aW[j] = v.l[0];
    }
    const char* base = s + L2F_O + 2 * wv * L2RST + ln12;
    const char* Ph = base + 8 * h;
    const char* Pa = base + (h ? 2 * L2RST : 0);
    const char* Pb = base + (h ? 2 * L2RST : L2RST);
    char* slot = s + RELAY_O + (wv * 32 + ln) * 48;
#pragma unroll
    for (int r = 0; r < 2; ++r) {
      f32x16 cF = {}, cW = {};
      conv12f8<L2RST, 4080>(aF, aW, Ph, Pa, Pb, r * L2RST, cF, cW);
      const int cidx = r;   // which half computes this call
      if (cidx == 0) {
        if (h) {            // h1 sends its ci4-7 (F then W) as bf16
          uint4 pay;
          pay.x = cvtpk(fmaxf(cF[0], 0.f), fmaxf(cF[1], 0.f));
          pay.y = cvtpk(fmaxf(cF[2], 0.f), fmaxf(cF[3], 0.f));
          pay.z = cvtpk(fmaxf(cW[0], 0.f), fmaxf(cW[1], 0.f));
          pay.w = cvtpk(fmaxf(cW[2], 0.f), fmaxf(cW[3], 0.f));
          *(uint4*)slot = pay;
        }
      } else {
        if (!h) {           // h0 sends ci0-3 + ci8-11 (F then W)
          uint4 pa, pb;
          pa.x = cvtpk(fmaxf(cF[0], 0.f), fmaxf(cF[1], 0.f));
          pa.y = cvtpk(fmaxf(cF[2], 0.f), fmaxf(cF[3], 0.f));
          pa.z = cvtpk(fmaxf(cF[4], 0.f), fmaxf(cF[5], 0.f));
          pa.w = cvtpk(fmaxf(cF[6], 0.f), fmaxf(cF[7], 0.f));
          pb.x = cvtpk(fmaxf(cW[0], 0.f), fmaxf(cW[1], 0.f));
          pb.y = cvtpk(fmaxf(cW[2], 0.f), fmaxf(cW[3], 0.f));
          pb.z = cvtpk(fmaxf(cW[4], 0.f), fmaxf(cW[5], 0.f));
          pb.w = cvtpk(fmaxf(cW[6], 0.f), fmaxf(cW[7], 0.f));
          *(uint4*)slot = pa;
          *(uint4*)(slot + 16) = pb;
        }
      }
      asm volatile("s_waitcnt lgkmcnt(0)" ::: "memory");
      if (h == cidx) {
        float F[12], Wv[12];
        if (cidx == 0) {    // h0 computes: own ci0-3 & ci8-11; relayed ci4-7
          const uint4 pay = *(const uint4*)slot;
#pragma unroll
          for (int c2 = 0; c2 < 4; ++c2) {
            F[c2]      = fmaxf(cF[c2], 0.f);
            F[8 + c2]  = fmaxf(cF[4 + c2], 0.f);
            Wv[c2]     = fmaxf(cW[c2], 0.f);
            Wv[8 + c2] = fmaxf(cW[4 + c2], 0.f);
          }
          F[4] = lo16(pay.x);  F[5] = hi16(pay.x);
          F[6] = lo16(pay.y);  F[7] = hi16(pay.y);
          Wv[4] = lo16(pay.z); Wv[5] = hi16(pay.z);
          Wv[6] = lo16(pay.w); Wv[7] = hi16(pay.w);
        } else {            // h1 computes: own ci4-7; relayed ci0-3 & ci8-11
          const uint4 pa = *(const uint4*)slot;
          const uint4 pb = *(const uint4*)(slot + 16);
#pragma unroll
          for (int c2 = 0; c2 < 4; ++c2) {
            F[4 + c2]  = fmaxf(cF[c2], 0.f);
            Wv[4 + c2] = fmaxf(cW[c2], 0.f);
          }
          F[0] = lo16(pa.x);   F[1] = hi16(pa.x);
          F[2] = lo16(pa.y);   F[3] = hi16(pa.y);
          F[8] = lo16(pa.z);   F[9] = hi16(pa.z);
          F[10] = lo16(pa.w);  F[11] = hi16(pa.w);
          Wv[0] = lo16(pb.x);  Wv[1] = hi16(pb.x);
          Wv[2] = lo16(pb.y);  Wv[3] = hi16(pb.y);
          Wv[8] = lo16(pb.z);  Wv[9] = hi16(pb.z);
          Wv[10] = lo16(pb.w); Wv[11] = hi16(pb.w);
        }
        // W logits are pre-scaled by 1/ln2 -> exp2 is exact softmax
        float m = 0.f;
#pragma unroll
        for (int c2 = 0; c2 < 12; ++c2) m = fmaxf(m, Wv[c2]);
        float sum = 0.f, s0 = 0.f, s1 = 0.f;
#pragma unroll
        for (int c2 = 0; c2 < 12; ++c2) {
          const float e = exp2f(Wv[c2] - m);
          sum += e;
          if (c2 < 6) s0 = fmaf(F[c2], e, s0);
          else        s1 = fmaf(F[c2], e, s1);
        }
        const float inv = 1.f / sum;
        const unsigned pg = cvtpk(s0 * inv, s1 * inv);
        const int gy = Y0 + 2 * wv + r;
        const int gx = X0 + ln;
        if (ln < TX && (unsigned)gx < WW) {
          green[((b * 2 + 0) * HH + gy) * WW + gx] = (unsigned short)pg;
          green[((b * 2 + 1) * HH + gy) * WW + gx] = (unsigned short)(pg >> 16);
        }
      }
    }
  }
}

// ---------------- chroma conv 2->6 + pixel-shuffle assembly ----------------
__global__ __launch_bounds__(256)
void assemble_kernel(const float* __restrict__ mosaic, const unsigned short* __restrict__ green,
                     const float* __restrict__ cw0, float* __restrict__ out) {
  const int t = blockIdx.x * 256 + threadIdx.x;
  const int x = t & (WW - 1);
  const int y = (t >> 9) & (HH - 1);
  const int b = t >> 18;

  const int p = y * WW + x;
  const float* __restrict__ mb = mosaic + (size_t)b * 4 * HH * WW;
  const unsigned short* __restrict__ gb = green + (size_t)b * 2 * HH * WW;

  const float m0 = mb[p];
  const float m1 = mb[HH * WW + p];
  const float m2 = mb[2 * HH * WW + p];
  const float m3 = mb[3 * HH * WW + p];
  const float g0 = bf2f(gb[p]);
  const float g1 = bf2f(gb[HH * WW + p]);

  float cd[6] = {0.f, 0.f, 0.f, 0.f, 0.f, 0.f};
#pragma unroll
  for (int ky = 0; ky < 3; ++ky) {
#pragma unroll
    for (int kx = 0; kx < 3; ++kx) {
      const int yy = y + ky - 1, xx = x + kx - 1;
      float c0 = 0.f, c1 = 0.f;
      if ((unsigned)yy < HH && (unsigned)xx < WW) {
        const int q = yy * WW + xx;
        c0 = mb[HH * WW + q]     - bf2f(gb[q]);
        c1 = mb[2 * HH * WW + q] - bf2f(gb[HH * WW + q]);
      }
      const int k = ky * 3 + kx;
#pragma unroll
      for (int o = 0; o < 6; ++o) {
        cd[o] = fmaf(c0, cw0[(o * 2 + 0) * 9 + k], cd[o]);
        cd[o] = fmaf(c1, cw0[(o * 2 + 1) * 9 + k], cd[o]);
      }
    }
  }
  const float cp0 = cd[0] + m0;
  const float cp1 = cd[1] + g1;
  const float cp2 = cd[2] + m3;
  const float cp3 = cd[3] + m0;
  const float cp4 = cd[4] + g0;
  const float cp5 = cd[5] + m3;

  const int W2 = 2 * WW;
  const size_t plane = (size_t)(2 * HH) * W2;
  size_t base = ((size_t)(b * 3) * (2 * HH) + 2 * y) * W2 + 2 * x;
  *(float2*)(out + base)              = make_float2(cp0, m1);
  *(float2*)(out + base + W2)         = make_float2(cp1, cp2);
  *(float2*)(out + base + plane)      = make_float2(m0, g0);
  *(float2*)(out + base + plane + W2) = make_float2(g1, m3);
  *(float2*)(out + base + 2 * plane)      = make_float2(cp3, cp4);
  *(float2*)(out + base + 2 * plane + W2) = make_float2(m2, cp5);
}

extern "C" void kernel_launch(void* const* d_in, const int* in_sizes, int n_in,
                              void* d_out, int out_size, void* d_ws, size_t ws_size,
                              hipStream_t stream) {
  const float* mosaic = (const float*)d_in[0];
  const float* fw0 = (const float*)d_in[1];
  const float* fw1 = (const float*)d_in[2];
  const float* fw2 = (const float*)d_in[3];
  const float* ww0 = (const float*)d_in[4];
  const float* ww1 = (const float*)d_in[5];
  const float* ww2 = (const float*)d_in[6];
  const float* cw0 = (const float*)d_in[7];

  uint4* wsf = (uint4*)((char*)d_ws + 32768);
  unsigned short* green = (unsigned short*)((char*)d_ws + 67584);
  float* out = (float*)d_out;

  wt_kernel<<<8, 256, 0, stream>>>(fw0, fw1, fw2, ww0, ww1, ww2, wsf);
  green_kernel<<<16 * 64 * 19, 256, 0, stream>>>(mosaic, wsf, green);
  assemble_kernel<<<(16 * HH * WW) / 256, 256, 0, stream>>>(mosaic, green, cw0, out);
}

// Round 9
// 225.467 us; speedup vs baseline: 1.3323x; 1.0506x over previous
//
#include <hip/hip_runtime.h>
#include <cstdint>

#define HH 512
#define WW 512
#define TX 58          // output tile width; 9 tiles cover 512 (last partial)
// grid = 16 * 64 * 9 = 9216 blocks

typedef __attribute__((ext_vector_type(8)))  short    short8;
typedef __attribute__((ext_vector_type(16))) float    f32x16;
typedef __attribute__((ext_vector_type(2)))  unsigned u32x2;
typedef long long lng;

union FragU { uint4 u; short8 s; };
union U4L   { uint4 u; lng l[2]; };
union B8U   { u32x2 u2[2]; short8 s; };
union BL    { unsigned w[2]; lng l; };

// ---- LDS layout (bytes) ----
// fp8 act slot = 12B (ci0-3 @0, ci4-7 @4, ci8-11 @8)
#define L1F_O  0        // 12 rows x 62 px x 12B
#define L1W_O  8928
#define L1RST  744
#define MOS_O  17856    // 14 rows x 64 px x 8B bf16 (dead after L1 pass)
#define MOSR   512
#define L2F_O  17856    // aliases mosaic; 10 rows x 60 px x 12B
#define L2W_O  25056
#define L2RST  720
#define RELAY_O 0       // aliases dead L1 during L3 phase; 128 slots x 48B
#define SMEMB  32256    // <= 32768 -> 5 blocks/CU

__device__ __forceinline__ unsigned cvtpk(float a, float b) {
  unsigned r;
  asm("v_cvt_pk_bf16_f32 %0, %1, %2" : "=v"(r) : "v"(a), "v"(b));
  return r;
}
__device__ __forceinline__ unsigned rpk8(float a, float b, float c, float d, bool im) {
  int r = __builtin_amdgcn_cvt_pk_fp8_f32(fmaxf(a, 0.f), fmaxf(b, 0.f), 0, false);
  r = __builtin_amdgcn_cvt_pk_fp8_f32(fmaxf(c, 0.f), fmaxf(d, 0.f), r, true);
  return im ? (unsigned)r : 0u;
}
__device__ __forceinline__ unsigned short f2bf(float f) {
  union { float f; unsigned u; } v; v.f = f;
  unsigned r = v.u + 0x7fffu + ((v.u >> 16) & 1u);
  return (unsigned short)(r >> 16);
}
__device__ __forceinline__ float bf2f(unsigned short b) {
  union { unsigned u; float f; } v; v.u = ((unsigned)b) << 16;
  return v.f;
}
__device__ __forceinline__ float lo16(unsigned u) {
  union { unsigned v; float f; } x; x.v = u << 16; return x.f;
}
__device__ __forceinline__ float hi16(unsigned u) {
  union { unsigned v; float f; } x; x.v = u & 0xffff0000u; return x.f;
}
__device__ __forceinline__ lng rd8(const char* p) {
  BL t;
  t.w[0] = *(const unsigned*)p;
  t.w[1] = *(const unsigned*)(p + 4);
  return t.l;
}

// ---------------- weight fragment packer (mapping unchanged since round 6) ----------------
// f 0-2: L1 merged bf16 (ky=f), rows 0-11 = fw0 co, 12-23 = ww0 co;
//        slot sq = 2h + e/4 -> kx = sq (sq==3 zero). 16B/lane.
// f 3-9: L2 F j / 10-16: L2 W j / 17-23: L3 F j / 24-30: L3 W j — fp8, 8B/lane.
// L3 W weights (f 24-30) pre-scaled by 1/ln2 so softmax uses exp2 directly.
// fp8 quads (27, quad q covers kappa 4q..4q+3; kappa = tap*12+ci;
// off(q) = (q/9)*RST + 4*(q%9)). (j,h) -> byte-adjacent quad pair:
//   j0:(0,1)/(2,3) j1:(4,5)/(6,7) j2:(9,10)/(11,12) j3:(13,14)/(15,16)
//   j4:(18,19)/(20,21) j5:(22,23)/(24,25) j6:(8,17)split / (26,pad)
__global__ void wt_kernel(const float* __restrict__ fw0, const float* __restrict__ fw1,
                          const float* __restrict__ fw2, const float* __restrict__ ww0,
                          const float* __restrict__ ww1, const float* __restrict__ ww2,
                          uint4* __restrict__ wsf) {
  int t = blockIdx.x * 256 + threadIdx.x;
  if (t >= 31 * 64) return;
  int f = t >> 6, lane = t & 63;
  int h = (lane >> 5) & 1, m = lane & 31;
  uint4 o = make_uint4(0, 0, 0, 0);
  if (f < 3) {
    unsigned short v[8];
#pragma unroll
    for (int e = 0; e < 8; ++e) {
      int sq = 2 * h + (e >> 2);
      int c4 = e & 3;
      float w = 0.f;
      if (sq < 3 && m < 24) {
        w = (m < 12) ? fw0[(m * 4 + c4) * 9 + f * 3 + sq]
                     : ww0[((m - 12) * 4 + c4) * 9 + f * 3 + sq];
      }
      v[e] = f2bf(w);
    }
    o.x = (unsigned)v[0] | ((unsigned)v[1] << 16);
    o.y = (unsigned)v[2] | ((unsigned)v[3] << 16);
    o.z = (unsigned)v[4] | ((unsigned)v[5] << 16);
    o.w = (unsigned)v[6] | ((unsigned)v[7] << 16);
  } else {
    const int PR[7][2][2] = {
      {{0, 1}, {2, 3}}, {{4, 5}, {6, 7}}, {{9, 10}, {11, 12}},
      {{13, 14}, {15, 16}}, {{18, 19}, {20, 21}}, {{22, 23}, {24, 25}},
      {{8, 17}, {26, -1}}};
    int fi = f - 3, layer = fi / 14, path = (fi % 14) / 7, j = fi % 7;
    const float* src = layer ? (path ? ww2 : fw2) : (path ? ww1 : fw1);
    const float scale = (layer == 1 && path == 1) ? 1.44269504f : 1.0f;
    float wv[8];
#pragma unroll
    for (int p = 0; p < 8; ++p) {
      int q = PR[j][h][p >> 2];
      int c = p & 3;
      float w = 0.f;
      if (q >= 0 && m < 12) {
        int kap = 4 * q + c;
        int tap = kap / 12, ci = kap % 12;
        w = src[(m * 12 + ci) * 9 + tap] * scale;
      }
      wv[p] = w;
    }
    int x = __builtin_amdgcn_cvt_pk_fp8_f32(wv[0], wv[1], 0, false);
    x = __builtin_amdgcn_cvt_pk_fp8_f32(wv[2], wv[3], x, true);
    int y = __builtin_amdgcn_cvt_pk_fp8_f32(wv[4], wv[5], 0, false);
    y = __builtin_amdgcn_cvt_pk_fp8_f32(wv[6], wv[7], y, true);
    o.x = (unsigned)x; o.y = (unsigned)y;
  }
  wsf[t] = o;
}

// dual fp8 12->12 conv group: 7 MFMAs each on F and W chains.
// Ph = base + 8h; Pa = base + (h?2RST:0); Pb = base + (h?2RST:RST).
template<int RST, int WIN>
__device__ __forceinline__ void conv12f8(const lng* aF, const lng* aW,
                                         const char* Ph, const char* Pa, const char* Pb,
                                         int imm, f32x16& cF, f32x16& cW) {
  const int IM[6] = {0, 16, RST, RST + 16, 2 * RST, 2 * RST + 16};
#pragma unroll
  for (int j = 0; j < 6; ++j) {
    lng bF = rd8(Ph + imm + IM[j]);
    lng bW = rd8(Ph + imm + IM[j] + WIN);
    cF = __builtin_amdgcn_mfma_f32_32x32x16_fp8_fp8(aF[j], bF, cF, 0, 0, 0);
    cW = __builtin_amdgcn_mfma_f32_32x32x16_fp8_fp8(aW[j], bW, cW, 0, 0, 0);
  }
  {
    BL bF, bW;
    bF.w[0] = *(const unsigned*)(Pa + imm + 32);
    bF.w[1] = *(const unsigned*)(Pb + imm + 32);
    bW.w[0] = *(const unsigned*)(Pa + imm + 32 + WIN);
    bW.w[1] = *(const unsigned*)(Pb + imm + 32 + WIN);
    cF = __builtin_amdgcn_mfma_f32_32x32x16_fp8_fp8(aF[6], bF.l, cF, 0, 0, 0);
    cW = __builtin_amdgcn_mfma_f32_32x32x16_fp8_fp8(aW[6], bW.l, cW, 0, 0, 0);
  }
}

// store M=12 C/D as fp8 (h0 regs0-3->ci0-3 @+0, regs4-7->ci8-11 @+8; h1 regs0-3->ci4-7 @+4)
// pO already includes +4h.
template<int WOUT>
__device__ __forceinline__ void store12f8(char* pO, int imm, const f32x16& cF,
                                          const f32x16& cW, bool im, int h) {
  *(unsigned*)(pO + imm) = rpk8(cF[0], cF[1], cF[2], cF[3], im);
  *(unsigned*)(pO + imm + WOUT) = rpk8(cW[0], cW[1], cW[2], cW[3], im);
  if (h == 0) {
    *(unsigned*)(pO + imm + 8) = rpk8(cF[4], cF[5], cF[6], cF[7], im);
    *(unsigned*)(pO + imm + WOUT + 8) = rpk8(cW[4], cW[5], cW[6], cW[7], im);
  }
}

// ---------------- fused 3-layer x 2-path conv via MFMA + in-reg softmax green ----------------
// launch_bounds(256,5): VGPR cap ~102 (kernel needs ~60) -> no spill; 5 blocks/CU via 32256B LDS.
__global__ __launch_bounds__(256, 5)
void green_kernel(const float* __restrict__ mosaic, const uint4* __restrict__ wsf,
                  unsigned short* __restrict__ green) {
  __shared__ __align__(16) char s[SMEMB];
  const int tid = threadIdx.x;
  const int lane = tid & 63;
  const int wv = __builtin_amdgcn_readfirstlane(tid >> 6);
  const int h = (lane >> 5) & 1, ln = lane & 31;
  const int ln8 = ln * 8, ln12 = ln * 12;
  const int bid = blockIdx.x;
  const int bx = bid % 9;
  const int t9 = bid / 9;
  const int by = t9 & 63, b = t9 >> 6;
  const int X0 = bx * TX, Y0 = by * 8;

  // ---- stage 0: mosaic tile 14x64, 4ch bf16-packed (8B/px), zero outside image ----
  {
    const float* mb = mosaic + (size_t)b * 4 * HH * WW;
    for (int p = tid; p < 14 * 64; p += 256) {
      int row = p >> 6, col = p & 63;
      int gy = Y0 + row - 3, gx = X0 + col - 3;
      float c0 = 0.f, c1 = 0.f, c2 = 0.f, c3 = 0.f;
      if ((unsigned)gy < HH && (unsigned)gx < WW) {
        const float* mp = mb + (size_t)gy * WW + gx;
        c0 = mp[0]; c1 = mp[HH * WW]; c2 = mp[2 * HH * WW]; c3 = mp[3 * HH * WW];
      }
      u32x2 w = { cvtpk(c0, c1), cvtpk(c2, c3) };
      *(u32x2*)(s + MOS_O + row * MOSR + col * 8) = w;
    }
  }
  __syncthreads();

  // ---- L1: 4->12 both paths in one bf16 MFMA (M: F 0-11, W 12-23), out 12x62 fp8 ----
  {
    FragU a3[3];
#pragma unroll
    for (int q = 0; q < 3; ++q) a3[q].u = wsf[q * 64 + lane];
    const char* pLo = s + MOS_O + 3 * wv * MOSR + ln8 + 16 * h;  // sem kx = 2h
    const char* pHi = s + MOS_O + 3 * wv * MOSR + ln8 + 8;       // sem kx=1 (h0); pad (h1)
    char* base = s + 3 * wv * L1RST + ln12;
    char* pA = base + L1F_O + 4 * h;                 // F d0 (h0) / F d1 (h1)
    char* pB = h ? base + L1W_O : base + L1F_O + 8;  // W d0 (h1) / F d2 (h0)
    char* pC = base + L1W_O + (h ? 8 : 4);           // W d2 (h1) / W d1 (h0)
    bool ck[2];
    ck[0] = (unsigned)(X0 + 0  + ln - 2) < WW;
    ck[1] = (unsigned)(X0 + 30 + ln - 2) < WW;
#pragma unroll
    for (int r = 0; r < 3; ++r) {
      const int ly = 3 * wv + r;
      const bool rowok = (unsigned)(Y0 + ly - 2) < HH;
#pragma unroll
      for (int g = 0; g < 2; ++g) {
        const int cb = g * 30;
        f32x16 c = {};
#pragma unroll
        for (int ky = 0; ky < 3; ++ky) {
          B8U bu;
          bu.u2[0] = *(const u32x2*)(pLo + (r + ky) * MOSR + cb * 8);
          bu.u2[1] = *(const u32x2*)(pHi + (r + ky) * MOSR + cb * 8);
          c = __builtin_amdgcn_mfma_f32_32x32x16_bf16(a3[ky].s, bu.s, c, 0, 0, 0);
        }
        const bool im = rowok && ck[g];
        *(unsigned*)(pA + r * L1RST + cb * 12) = rpk8(c[0], c[1], c[2], c[3], im);
        *(unsigned*)(pB + r * L1RST + cb * 12) = rpk8(c[4], c[5], c[6], c[7], im);
        *(unsigned*)(pC + r * L1RST + cb * 12) = rpk8(c[8], c[9], c[10], c[11], im);
      }
    }
  }
  __syncthreads();

  // ---- L2: 12->12 both chains fp8, out 10x60 ----
  {
    lng aF[7], aW[7];
#pragma unroll
    for (int j = 0; j < 7; ++j) {
      U4L u; u.u = wsf[(3 + j) * 64 + lane];  aF[j] = u.l[0];
      U4L v; v.u = wsf[(10 + j) * 64 + lane]; aW[j] = v.l[0];
    }
    const char* base = s + L1F_O + wv * L1RST + ln12;
    const char* Ph = base + 8 * h;
    const char* Pa = base + (h ? 2 * L1RST : 0);
    const char* Pb = base + (h ? 2 * L1RST : L1RST);
    char* bO0 = s + L2F_O + wv * L2RST + ln12 + 4 * h;
    bool ck[2];
    ck[0] = (unsigned)(X0 + 0  + ln - 1) < WW;
    ck[1] = (unsigned)(X0 + 28 + ln - 1) < WW;
#pragma unroll
    for (int i = 0; i < 3; ++i) {
      const int ly = wv + 4 * i;
      if (ly < 10) {
        const bool rowok = (unsigned)(Y0 + ly - 1) < HH;
#pragma unroll
        for (int g = 0; g < 2; ++g) {
          const int cb = g * 28;
          f32x16 cF = {}, cW = {};
          conv12f8<L1RST, 8928>(aF, aW, Ph, Pa, Pb, i * 4 * L1RST + cb * 12, cF, cW);
          store12f8<7200>(bO0, i * 4 * L2RST + cb * 12, cF, cW, rowok && ck[g], h);
        }
      }
    }
  }
  __syncthreads();

  // ---- L3: 12->12 both chains fp8, in-register + relay softmax, out 8x58 ----
  {
    lng aF[7], aW[7];
#pragma unroll
    for (int j = 0; j < 7; ++j) {
      U4L u; u.u = wsf[(17 + j) * 64 + lane]; aF[j] = u.l[0];
      U4L v; v.u = wsf[(24 + j) * 64 + lane]; aW[j] = v.l[0];
    }
    const char* base = s + L2F_O + 2 * wv * L2RST + ln12;
    const char* Ph = base + 8 * h;
    const char* Pa = base + (h ? 2 * L2RST : 0);
    const char* Pb = base + (h ? 2 * L2RST : L2RST);
    char* slot = s + RELAY_O + (wv * 32 + ln) * 48;
#pragma unroll
    for (int r = 0; r < 2; ++r) {
#pragma unroll
      for (int g = 0; g < 2; ++g) {
        const int cb = g * 26;
        f32x16 cF = {}, cW = {};
        conv12f8<L2RST, 7200>(aF, aW, Ph, Pa, Pb, r * L2RST + cb * 12, cF, cW);
        const int cidx = g & 1;   // which half computes this call
        if (cidx == 0) {
          if (h) {            // h1 sends its ci4-7 (F then W) as bf16
            uint4 pay;
            pay.x = cvtpk(fmaxf(cF[0], 0.f), fmaxf(cF[1], 0.f));
            pay.y = cvtpk(fmaxf(cF[2], 0.f), fmaxf(cF[3], 0.f));
            pay.z = cvtpk(fmaxf(cW[0], 0.f), fmaxf(cW[1], 0.f));
            pay.w = cvtpk(fmaxf(cW[2], 0.f), fmaxf(cW[3], 0.f));
            *(uint4*)slot = pay;
          }
        } else {
          if (!h) {           // h0 sends ci0-3 + ci8-11 (F then W)
            uint4 pa, pb;
            pa.x = cvtpk(fmaxf(cF[0], 0.f), fmaxf(cF[1], 0.f));
            pa.y = cvtpk(fmaxf(cF[2], 0.f), fmaxf(cF[3], 0.f));
            pa.z = cvtpk(fmaxf(cF[4], 0.f), fmaxf(cF[5], 0.f));
            pa.w = cvtpk(fmaxf(cF[6], 0.f), fmaxf(cF[7], 0.f));
            pb.x = cvtpk(fmaxf(cW[0], 0.f), fmaxf(cW[1], 0.f));
            pb.y = cvtpk(fmaxf(cW[2], 0.f), fmaxf(cW[3], 0.f));
            pb.z = cvtpk(fmaxf(cW[4], 0.f), fmaxf(cW[5], 0.f));
            pb.w = cvtpk(fmaxf(cW[6], 0.f), fmaxf(cW[7], 0.f));
            *(uint4*)slot = pa;
            *(uint4*)(slot + 16) = pb;
          }
        }
        asm volatile("s_waitcnt lgkmcnt(0)" ::: "memory");
        if (h == cidx) {
          float F[12], Wv[12];
          if (cidx == 0) {    // h0 computes: own ci0-3 & ci8-11; relayed ci4-7
            const uint4 pay = *(const uint4*)slot;
#pragma unroll
            for (int c2 = 0; c2 < 4; ++c2) {
              F[c2]      = fmaxf(cF[c2], 0.f);
              F[8 + c2]  = fmaxf(cF[4 + c2], 0.f);
              Wv[c2]     = fmaxf(cW[c2], 0.f);
              Wv[8 + c2] = fmaxf(cW[4 + c2], 0.f);
            }
            F[4] = lo16(pay.x);  F[5] = hi16(pay.x);
            F[6] = lo16(pay.y);  F[7] = hi16(pay.y);
            Wv[4] = lo16(pay.z); Wv[5] = hi16(pay.z);
            Wv[6] = lo16(pay.w); Wv[7] = hi16(pay.w);
          } else {            // h1 computes: own ci4-7; relayed ci0-3 & ci8-11
            const uint4 pa = *(const uint4*)slot;
            const uint4 pb = *(const uint4*)(slot + 16);
#pragma unroll
            for (int c2 = 0; c2 < 4; ++c2) {
              F[4 + c2]  = fmaxf(cF[c2], 0.f);
              Wv[4 + c2] = fmaxf(cW[c2], 0.f);
            }
            F[0] = lo16(pa.x);   F[1] = hi16(pa.x);
            F[2] = lo16(pa.y);   F[3] = hi16(pa.y);
            F[8] = lo16(pa.z);   F[9] = hi16(pa.z);
            F[10] = lo16(pa.w);  F[11] = hi16(pa.w);
            Wv[0] = lo16(pb.x);  Wv[1] = hi16(pb.x);
            Wv[2] = lo16(pb.y);  Wv[3] = hi16(pb.y);
            Wv[8] = lo16(pb.z);  Wv[9] = hi16(pb.z);
            Wv[10] = lo16(pb.w); Wv[11] = hi16(pb.w);
          }
          // W logits are pre-scaled by 1/ln2 -> exp2 is exact softmax
          float m = 0.f;
#pragma unroll
          for (int c2 = 0; c2 < 12; ++c2) m = fmaxf(m, Wv[c2]);
          float sum = 0.f, s0 = 0.f, s1 = 0.f;
#pragma unroll
          for (int c2 = 0; c2 < 12; ++c2) {
            const float e = exp2f(Wv[c2] - m);
            sum += e;
            if (c2 < 6) s0 = fmaf(F[c2], e, s0);
            else        s1 = fmaf(F[c2], e, s1);
          }
          const float inv = 1.f / sum;
          const unsigned pg = cvtpk(s0 * inv, s1 * inv);
          const int gy = Y0 + 2 * wv + r;
          const int gx = X0 + cb + ln;
          if ((unsigned)gx < WW) {
            green[((b * 2 + 0) * HH + gy) * WW + gx] = (unsigned short)pg;
            green[((b * 2 + 1) * HH + gy) * WW + gx] = (unsigned short)(pg >> 16);
          }
        }
      }
    }
  }
}

// ---------------- chroma conv 2->6 + pixel-shuffle assembly ----------------
__global__ __launch_bounds__(256)
void assemble_kernel(const float* __restrict__ mosaic, const unsigned short* __restrict__ green,
                     const float* __restrict__ cw0, float* __restrict__ out) {
  const int t = blockIdx.x * 256 + threadIdx.x;
  const int x = t & (WW - 1);
  const int y = (t >> 9) & (HH - 1);
  const int b = t >> 18;

  const int p = y * WW + x;
  const float* __restrict__ mb = mosaic + (size_t)b * 4 * HH * WW;
  const unsigned short* __restrict__ gb = green + (size_t)b * 2 * HH * WW;

  const float m0 = mb[p];
  const float m1 = mb[HH * WW + p];
  const float m2 = mb[2 * HH * WW + p];
  const float m3 = mb[3 * HH * WW + p];
  const float g0 = bf2f(gb[p]);
  const float g1 = bf2f(gb[HH * WW + p]);

  float cd[6] = {0.f, 0.f, 0.f, 0.f, 0.f, 0.f};
#pragma unroll
  for (int ky = 0; ky < 3; ++ky) {
#pragma unroll
    for (int kx = 0; kx < 3; ++kx) {
      const int yy = y + ky - 1, xx = x + kx - 1;
      float c0 = 0.f, c1 = 0.f;
      if ((unsigned)yy < HH && (unsigned)xx < WW) {
        const int q = yy * WW + xx;
        c0 = mb[HH * WW + q]     - bf2f(gb[q]);
        c1 = mb[2 * HH * WW + q] - bf2f(gb[HH * WW + q]);
      }
      const int k = ky * 3 + kx;
#pragma unroll
      for (int o = 0; o < 6; ++o) {
        cd[o] = fmaf(c0, cw0[(o * 2 + 0) * 9 + k], cd[o]);
        cd[o] = fmaf(c1, cw0[(o * 2 + 1) * 9 + k], cd[o]);
      }
    }
  }
  const float cp0 = cd[0] + m0;
  const float cp1 = cd[1] + g1;
  const float cp2 = cd[2] + m3;
  const float cp3 = cd[3] + m0;
  const float cp4 = cd[4] + g0;
  const float cp5 = cd[5] + m3;

  const int W2 = 2 * WW;
  const size_t plane = (size_t)(2 * HH) * W2;
  size_t base = ((size_t)(b * 3) * (2 * HH) + 2 * y) * W2 + 2 * x;
  *(float2*)(out + base)              = make_float2(cp0, m1);
  *(float2*)(out + base + W2)         = make_float2(cp1, cp2);
  *(float2*)(out + base + plane)      = make_float2(m0, g0);
  *(float2*)(out + base + plane + W2) = make_float2(g1, m3);
  *(float2*)(out + base + 2 * plane)      = make_float2(cp3, cp4);
  *(float2*)(out + base + 2 * plane + W2) = make_float2(m2, cp5);
}

extern "C" void kernel_launch(void* const* d_in, const int* in_sizes, int n_in,
                              void* d_out, int out_size, void* d_ws, size_t ws_size,
                              hipStream_t stream) {
  const float* mosaic = (const float*)d_in[0];
  const float* fw0 = (const float*)d_in[1];
  const float* fw1 = (const float*)d_in[2];
  const float* fw2 = (const float*)d_in[3];
  const float* ww0 = (const float*)d_in[4];
  const float* ww1 = (const float*)d_in[5];
  const float* ww2 = (const float*)d_in[6];
  const float* cw0 = (const float*)d_in[7];

  uint4* wsf = (uint4*)((char*)d_ws + 32768);
  unsigned short* green = (unsigned short*)((char*)d_ws + 67584);
  float* out = (float*)d_out;

  wt_kernel<<<8, 256, 0, stream>>>(fw0, fw1, fw2, ww0, ww1, ww2, wsf);
  green_kernel<<<16 * 64 * 9, 256, 0, stream>>>(mosaic, wsf, green);
  assemble_kernel<<<(16 * HH * WW) / 256, 256, 0, stream>>>(mosaic, green, cw0, out);
}

// Round 10
// 202.597 us; speedup vs baseline: 1.4827x; 1.1129x over previous
//
#include <hip/hip_runtime.h>
#include <cstdint>

#define HH 512
#define WW 512
#define TX 58          // output tile width; 9 tiles cover 512 (last partial)
// grid = 16 * 64 * 9 = 9216 blocks

typedef __attribute__((ext_vector_type(8)))  short    short8;
typedef __attribute__((ext_vector_type(16))) float    f32x16;
typedef __attribute__((ext_vector_type(4)))  float    f32x4;
typedef __attribute__((ext_vector_type(2)))  unsigned u32x2;
typedef __attribute__((ext_vector_type(8)))  int      int8v;

union FragU { uint4 u; short8 s; };
union B8U   { u32x2 u2[2]; short8 s; };
union AF8   { uint4 u[2]; int8v v; };
union BF8   { unsigned d[8]; int8v v; };

// ---- LDS layout (bytes); fp8 act slot = 12B (ci0-3 @0, ci4-7 @4, ci8-11 @8) ----
#define L1F_O  0        // 12 rows x 62 px x 12B
#define L1W_O  8928
#define L1RST  744
#define MOS_O  17856    // 14 rows x 64 px x 8B bf16 (dead after L1)
#define MOSR   512
#define L2F_O  17856    // aliases mosaic; 10 rows x 60 px x 12B
#define L2W_O  25056
#define L2RST  720
#define RELAY_O 0       // aliases dead L1 during L3; 4 waves x 64 slots x 48B
#define SMEMB  32320    // 32256 + tail-read pad

#define MFMA_SC(A, B, C) \
  __builtin_amdgcn_mfma_scale_f32_16x16x128_f8f6f4((A), (B), (C), 0, 0, 0, 0x7F7F7F7Fu, 0, 0x7F7F7F7Fu)

__device__ __forceinline__ unsigned cvtpk(float a, float b) {
  unsigned r;
  asm("v_cvt_pk_bf16_f32 %0, %1, %2" : "=v"(r) : "v"(a), "v"(b));
  return r;
}
__device__ __forceinline__ unsigned rpk8(float a, float b, float c, float d, bool im) {
  int r = __builtin_amdgcn_cvt_pk_fp8_f32(fmaxf(a, 0.f), fmaxf(b, 0.f), 0, false);
  r = __builtin_amdgcn_cvt_pk_fp8_f32(fmaxf(c, 0.f), fmaxf(d, 0.f), r, true);
  return im ? (unsigned)r : 0u;
}
__device__ __forceinline__ unsigned short f2bf(float f) {
  union { float f; unsigned u; } v; v.f = f;
  unsigned r = v.u + 0x7fffu + ((v.u >> 16) & 1u);
  return (unsigned short)(r >> 16);
}
__device__ __forceinline__ float bf2f(unsigned short b) {
  union { unsigned u; float f; } v; v.u = ((unsigned)b) << 16;
  return v.f;
}
__device__ __forceinline__ float lo16(unsigned u) {
  union { unsigned v; float f; } x; x.v = u << 16; return x.f;
}
__device__ __forceinline__ float hi16(unsigned u) {
  union { unsigned v; float f; } x; x.v = u & 0xffff0000u; return x.f;
}

// ---------------- weight packer ----------------
// t 0-191: L1 merged bf16 frags (f = t>>6 = ky), rows 0-11 fw0, 12-23 ww0;
//          slot sq = 2h + e/4 -> kx = sq (sq==3 zero); uint4/lane (entries 0-191).
// t 192-447: scaled K=128 frags, sid = {L2F,L2W,L3F,L3W}; 32B/lane at entries
//          192 + sid*128 + lane*2. Lane: m = lane&15 (co), kg = lane>>4.
//   kg<3 : e (0-31) -> window row kg byte e: dx=e/12, ci=e%12, tap=kg*3+dx.
//   kg==3: e=8i+j, valid i<3,j<4: tap=i*3+2, ci=8+j (row-tails); else 0.
// L3 W set pre-scaled 1/ln2 (softmax via exp2).
__global__ void wt_kernel(const float* __restrict__ fw0, const float* __restrict__ fw1,
                          const float* __restrict__ fw2, const float* __restrict__ ww0,
                          const float* __restrict__ ww1, const float* __restrict__ ww2,
                          uint4* __restrict__ wsf) {
  int t = blockIdx.x * 256 + threadIdx.x;
  if (t >= 448) return;
  if (t < 192) {
    int f = t >> 6, lane = t & 63;
    int h = (lane >> 5) & 1, m = lane & 31;
    unsigned short v[8];
#pragma unroll
    for (int e = 0; e < 8; ++e) {
      int sq = 2 * h + (e >> 2);
      int c4 = e & 3;
      float w = 0.f;
      if (sq < 3 && m < 24) {
        w = (m < 12) ? fw0[(m * 4 + c4) * 9 + f * 3 + sq]
                     : ww0[((m - 12) * 4 + c4) * 9 + f * 3 + sq];
      }
      v[e] = f2bf(w);
    }
    uint4 o;
    o.x = (unsigned)v[0] | ((unsigned)v[1] << 16);
    o.y = (unsigned)v[2] | ((unsigned)v[3] << 16);
    o.z = (unsigned)v[4] | ((unsigned)v[5] << 16);
    o.w = (unsigned)v[6] | ((unsigned)v[7] << 16);
    wsf[t] = o;
  } else {
    int u = t - 192, sid = u >> 6, lane = u & 63;
    int m = lane & 15, kg = lane >> 4;
    int layer = sid >> 1, path = sid & 1;
    const float* src = layer ? (path ? ww2 : fw2) : (path ? ww1 : fw1);
    const float scale = (layer == 1 && path == 1) ? 1.44269504f : 1.0f;
    unsigned d[8];
#pragma unroll
    for (int k = 0; k < 8; ++k) {
      float w4[4];
#pragma unroll
      for (int j4 = 0; j4 < 4; ++j4) {
        int e = 4 * k + j4;
        float w = 0.f;
        if (m < 12) {
          if (kg < 3) {
            int dx = e / 12, ci = e % 12, tap = kg * 3 + dx;
            w = src[(m * 12 + ci) * 9 + tap] * scale;
          } else {
            int i = e >> 3, j = e & 7;
            if (i < 3 && j < 4) {
              int tap = i * 3 + 2, ci = 8 + j;
              w = src[(m * 12 + ci) * 9 + tap] * scale;
            }
          }
        }
        w4[j4] = w;
      }
      int x = __builtin_amdgcn_cvt_pk_fp8_f32(w4[0], w4[1], 0, false);
      x = __builtin_amdgcn_cvt_pk_fp8_f32(w4[2], w4[3], x, true);
      d[k] = (unsigned)x;
    }
    uint4* dst = wsf + 192 + sid * 128 + lane * 2;
    dst[0] = make_uint4(d[0], d[1], d[2], d[3]);
    dst[1] = make_uint4(d[4], d[5], d[6], d[7]);
  }
}

// ---------------- fused 3-layer x 2-path conv (MX K=128 MFMA) + softmax green ----------------
__global__ __launch_bounds__(256, 5)
void green_kernel(const float* __restrict__ mosaic, const uint4* __restrict__ wsf,
                  unsigned short* __restrict__ green) {
  __shared__ __align__(16) char s[SMEMB];
  const int tid = threadIdx.x;
  const int lane = tid & 63;
  const int wv = __builtin_amdgcn_readfirstlane(tid >> 6);
  const int h = (lane >> 5) & 1, ln = lane & 31;
  const int ln8 = ln * 8, ln12 = ln * 12;
  const int pxl = lane & 15, kg = lane >> 4;
  const int bid = blockIdx.x;
  const int bx = bid % 9;
  const int t9 = bid / 9;
  const int by = t9 & 63, b = t9 >> 6;
  const int X0 = bx * TX, Y0 = by * 8;

  // ---- stage 0: mosaic tile 14x64, 4ch bf16-packed (8B/px), zero outside image ----
  {
    const float* mb = mosaic + (size_t)b * 4 * HH * WW;
    for (int p = tid; p < 14 * 64; p += 256) {
      int row = p >> 6, col = p & 63;
      int gy = Y0 + row - 3, gx = X0 + col - 3;
      float c0 = 0.f, c1 = 0.f, c2 = 0.f, c3 = 0.f;
      if ((unsigned)gy < HH && (unsigned)gx < WW) {
        const float* mp = mb + (size_t)gy * WW + gx;
        c0 = mp[0]; c1 = mp[HH * WW]; c2 = mp[2 * HH * WW]; c3 = mp[3 * HH * WW];
      }
      u32x2 w = { cvtpk(c0, c1), cvtpk(c2, c3) };
      *(u32x2*)(s + MOS_O + row * MOSR + col * 8) = w;
    }
  }
  __syncthreads();

  // ---- L1: 4->12 both paths in one bf16 MFMA (M: F 0-11, W 12-23), out 12x62 fp8 ----
  {
    FragU a3[3];
#pragma unroll
    for (int q = 0; q < 3; ++q) a3[q].u = wsf[q * 64 + lane];
    const char* pLo = s + MOS_O + 3 * wv * MOSR + ln8 + 16 * h;
    const char* pHi = s + MOS_O + 3 * wv * MOSR + ln8 + 8;
    char* base = s + 3 * wv * L1RST + ln12;
    char* pA = base + L1F_O + 4 * h;
    char* pB = h ? base + L1W_O : base + L1F_O + 8;
    char* pC = base + L1W_O + (h ? 8 : 4);
    bool ck[2];
    ck[0] = (unsigned)(X0 + 0  + ln - 2) < WW;
    ck[1] = (unsigned)(X0 + 30 + ln - 2) < WW;
#pragma unroll
    for (int r = 0; r < 3; ++r) {
      const int ly = 3 * wv + r;
      const bool rowok = (unsigned)(Y0 + ly - 2) < HH;
#pragma unroll
      for (int g = 0; g < 2; ++g) {
        const int cb = g * 30;
        f32x16 c = {};
#pragma unroll
        for (int ky = 0; ky < 3; ++ky) {
          B8U bu;
          bu.u2[0] = *(const u32x2*)(pLo + (r + ky) * MOSR + cb * 8);
          bu.u2[1] = *(const u32x2*)(pHi + (r + ky) * MOSR + cb * 8);
          c = __builtin_amdgcn_mfma_f32_32x32x16_bf16(a3[ky].s, bu.s, c, 0, 0, 0);
        }
        const bool im = rowok && ck[g];
        *(unsigned*)(pA + r * L1RST + cb * 12) = rpk8(c[0], c[1], c[2], c[3], im);
        *(unsigned*)(pB + r * L1RST + cb * 12) = rpk8(c[4], c[5], c[6], c[7], im);
        *(unsigned*)(pC + r * L1RST + cb * 12) = rpk8(c[8], c[9], c[10], c[11], im);
      }
    }
  }
  __syncthreads();

  // ---- L2: 12->12 both chains, ONE scaled MFMA per 16px per chain, out 10x60 ----
  {
    AF8 aF, aW;
    aF.u[0] = wsf[192 + lane * 2]; aF.u[1] = wsf[193 + lane * 2];
    aW.u[0] = wsf[320 + lane * 2]; aW.u[1] = wsf[321 + lane * 2];
    const int c0 = (wv == 0) ? 0 : (wv == 1) ? 16 : (wv == 2) ? 32 : 44;
    int o0, o1, o2, o3;
    if (kg < 3) { o0 = kg * L1RST + pxl * 12; o1 = o0 + 8; o2 = o0 + 16; o3 = o0 + 24; }
    else        { o0 = (pxl + 2) * 12 + 8; o1 = o0 + L1RST; o2 = o1 + L1RST; o3 = o2; }
    const char* P0 = s + L1F_O + c0 * 12 + o0;
    const char* P1 = s + L1F_O + c0 * 12 + o1;
    const char* P2 = s + L1F_O + c0 * 12 + o2;
    const char* P3 = s + L1F_O + c0 * 12 + o3;
    const bool ckx = (unsigned)(X0 + c0 + pxl - 1) < WW;
    char* pO = s + L2F_O + (c0 + pxl) * 12 + 4 * kg;
#pragma unroll
    for (int ly = 0; ly < 10; ++ly) {
      const int imm = ly * L1RST;
      BF8 bF, bW;
      bF.d[0] = *(const unsigned*)(P0 + imm);        bF.d[1] = *(const unsigned*)(P0 + imm + 4);
      bF.d[2] = *(const unsigned*)(P1 + imm);        bF.d[3] = *(const unsigned*)(P1 + imm + 4);
      bF.d[4] = *(const unsigned*)(P2 + imm);        bF.d[5] = *(const unsigned*)(P2 + imm + 4);
      bF.d[6] = *(const unsigned*)(P3 + imm);        bF.d[7] = *(const unsigned*)(P3 + imm + 4);
      bW.d[0] = *(const unsigned*)(P0 + imm + 8928); bW.d[1] = *(const unsigned*)(P0 + imm + 8932);
      bW.d[2] = *(const unsigned*)(P1 + imm + 8928); bW.d[3] = *(const unsigned*)(P1 + imm + 8932);
      bW.d[4] = *(const unsigned*)(P2 + imm + 8928); bW.d[5] = *(const unsigned*)(P2 + imm + 8932);
      bW.d[6] = *(const unsigned*)(P3 + imm + 8928); bW.d[7] = *(const unsigned*)(P3 + imm + 8932);
      f32x4 cF = {0.f, 0.f, 0.f, 0.f}, cW = {0.f, 0.f, 0.f, 0.f};
      cF = MFMA_SC(aF.v, bF.v, cF);
      cW = MFMA_SC(aW.v, bW.v, cW);
      const bool im = ckx && ((unsigned)(Y0 + ly - 1) < HH);
      if (kg < 3) {
        *(unsigned*)(pO + ly * L2RST)        = rpk8(cF[0], cF[1], cF[2], cF[3], im);
        *(unsigned*)(pO + ly * L2RST + 7200) = rpk8(cW[0], cW[1], cW[2], cW[3], im);
      }
    }
  }
  __syncthreads();

  // ---- L3: scaled MFMA + relay + all-lane softmax, out 8x58 ----
  {
    AF8 aF, aW;
    aF.u[0] = wsf[448 + lane * 2]; aF.u[1] = wsf[449 + lane * 2];
    aW.u[0] = wsf[576 + lane * 2]; aW.u[1] = wsf[577 + lane * 2];
    const int c0 = (wv == 0) ? 0 : (wv == 1) ? 16 : (wv == 2) ? 32 : 42;
    int o0, o1, o2, o3;
    if (kg < 3) { o0 = kg * L2RST + pxl * 12; o1 = o0 + 8; o2 = o0 + 16; o3 = o0 + 24; }
    else        { o0 = (pxl + 2) * 12 + 8; o1 = o0 + L2RST; o2 = o1 + L2RST; o3 = o2; }
    const char* P0 = s + L2F_O + c0 * 12 + o0;
    const char* P1 = s + L2F_O + c0 * 12 + o1;
    const char* P2 = s + L2F_O + c0 * 12 + o2;
    const char* P3 = s + L2F_O + c0 * 12 + o3;
    char* relay = s + RELAY_O + wv * 3072;
#pragma unroll
    for (int half = 0; half < 2; ++half) {
#pragma unroll
      for (int rr = 0; rr < 4; ++rr) {
        const int imm = (half * 4 + rr) * L2RST;
        BF8 bF, bW;
        bF.d[0] = *(const unsigned*)(P0 + imm);        bF.d[1] = *(const unsigned*)(P0 + imm + 4);
        bF.d[2] = *(const unsigned*)(P1 + imm);        bF.d[3] = *(const unsigned*)(P1 + imm + 4);
        bF.d[4] = *(const unsigned*)(P2 + imm);        bF.d[5] = *(const unsigned*)(P2 + imm + 4);
        bF.d[6] = *(const unsigned*)(P3 + imm);        bF.d[7] = *(const unsigned*)(P3 + imm + 4);
        bW.d[0] = *(const unsigned*)(P0 + imm + 7200); bW.d[1] = *(const unsigned*)(P0 + imm + 7204);
        bW.d[2] = *(const unsigned*)(P1 + imm + 7200); bW.d[3] = *(const unsigned*)(P1 + imm + 7204);
        bW.d[4] = *(const unsigned*)(P2 + imm + 7200); bW.d[5] = *(const unsigned*)(P2 + imm + 7204);
        bW.d[6] = *(const unsigned*)(P3 + imm + 7200); bW.d[7] = *(const unsigned*)(P3 + imm + 7204);
        f32x4 cF = {0.f, 0.f, 0.f, 0.f}, cW = {0.f, 0.f, 0.f, 0.f};
        cF = MFMA_SC(aF.v, bF.v, cF);
        cW = MFMA_SC(aW.v, bW.v, cW);
        if (kg < 3) {
          char* slot = relay + ((rr << 4) + pxl) * 48 + kg * 8;
          u32x2 fv = { cvtpk(fmaxf(cF[0], 0.f), fmaxf(cF[1], 0.f)),
                       cvtpk(fmaxf(cF[2], 0.f), fmaxf(cF[3], 0.f)) };
          u32x2 wvv = { cvtpk(fmaxf(cW[0], 0.f), fmaxf(cW[1], 0.f)),
                        cvtpk(fmaxf(cW[2], 0.f), fmaxf(cW[3], 0.f)) };
          *(u32x2*)slot = fv;
          *(u32x2*)(slot + 24) = wvv;
        }
      }
      asm volatile("s_waitcnt lgkmcnt(0)" ::: "memory");
      {
        const char* slot = relay + lane * 48;
        u32x2 f0 = *(const u32x2*)(slot);
        u32x2 f1 = *(const u32x2*)(slot + 8);
        u32x2 f2 = *(const u32x2*)(slot + 16);
        u32x2 w0 = *(const u32x2*)(slot + 24);
        u32x2 w1 = *(const u32x2*)(slot + 32);
        u32x2 w2 = *(const u32x2*)(slot + 40);
        float F[12], Wv[12];
        F[0] = lo16(f0.x);  F[1] = hi16(f0.x);  F[2] = lo16(f0.y);  F[3] = hi16(f0.y);
        F[4] = lo16(f1.x);  F[5] = hi16(f1.x);  F[6] = lo16(f1.y);  F[7] = hi16(f1.y);
        F[8] = lo16(f2.x);  F[9] = hi16(f2.x);  F[10] = lo16(f2.y); F[11] = hi16(f2.y);
        Wv[0] = lo16(w0.x); Wv[1] = hi16(w0.x); Wv[2] = lo16(w0.y); Wv[3] = hi16(w0.y);
        Wv[4] = lo16(w1.x); Wv[5] = hi16(w1.x); Wv[6] = lo16(w1.y); Wv[7] = hi16(w1.y);
        Wv[8] = lo16(w2.x); Wv[9] = hi16(w2.x); Wv[10] = lo16(w2.y); Wv[11] = hi16(w2.y);
        float m = 0.f;
#pragma unroll
        for (int c2 = 0; c2 < 12; ++c2) m = fmaxf(m, Wv[c2]);
        float sum = 0.f, s0 = 0.f, s1 = 0.f;
#pragma unroll
        for (int c2 = 0; c2 < 12; ++c2) {
          const float e = exp2f(Wv[c2] - m);   // W logits pre-scaled by 1/ln2
          sum += e;
          if (c2 < 6) s0 = fmaf(F[c2], e, s0);
          else        s1 = fmaf(F[c2], e, s1);
        }
        const float inv = 1.f / sum;
        const unsigned pg = cvtpk(s0 * inv, s1 * inv);
        const int gy = Y0 + half * 4 + kg;
        const int gx = X0 + c0 + pxl;
        if ((unsigned)gx < WW) {
          green[((b * 2 + 0) * HH + gy) * WW + gx] = (unsigned short)pg;
          green[((b * 2 + 1) * HH + gy) * WW + gx] = (unsigned short)(pg >> 16);
        }
      }
      asm volatile("s_waitcnt lgkmcnt(0)" ::: "memory");
    }
  }
}

// ---------------- chroma conv 2->6 + pixel-shuffle assembly ----------------
__global__ __launch_bounds__(256)
void assemble_kernel(const float* __restrict__ mosaic, const unsigned short* __restrict__ green,
                     const float* __restrict__ cw0, float* __restrict__ out) {
  const int t = blockIdx.x * 256 + threadIdx.x;
  const int x = t & (WW - 1);
  const int y = (t >> 9) & (HH - 1);
  const int b = t >> 18;

  const int p = y * WW + x;
  const float* __restrict__ mb = mosaic + (size_t)b * 4 * HH * WW;
  const unsigned short* __restrict__ gb = green + (size_t)b * 2 * HH * WW;

  const float m0 = mb[p];
  const float m1 = mb[HH * WW + p];
  const float m2 = mb[2 * HH * WW + p];
  const float m3 = mb[3 * HH * WW + p];
  const float g0 = bf2f(gb[p]);
  const float g1 = bf2f(gb[HH * WW + p]);

  float cd[6] = {0.f, 0.f, 0.f, 0.f, 0.f, 0.f};
#pragma unroll
  for (int ky = 0; ky < 3; ++ky) {
#pragma unroll
    for (int kx = 0; kx < 3; ++kx) {
      const int yy = y + ky - 1, xx = x + kx - 1;
      float c0 = 0.f, c1 = 0.f;
      if ((unsigned)yy < HH && (unsigned)xx < WW) {
        const int q = yy * WW + xx;
        c0 = mb[HH * WW + q]     - bf2f(gb[q]);
        c1 = mb[2 * HH * WW + q] - bf2f(gb[HH * WW + q]);
      }
      const int k = ky * 3 + kx;
#pragma unroll
      for (int o = 0; o < 6; ++o) {
        cd[o] = fmaf(c0, cw0[(o * 2 + 0) * 9 + k], cd[o]);
        cd[o] = fmaf(c1, cw0[(o * 2 + 1) * 9 + k], cd[o]);
      }
    }
  }
  const float cp0 = cd[0] + m0;
  const float cp1 = cd[1] + g1;
  const float cp2 = cd[2] + m3;
  const float cp3 = cd[3] + m0;
  const float cp4 = cd[4] + g0;
  const float cp5 = cd[5] + m3;

  const int W2 = 2 * WW;
  const size_t plane = (size_t)(2 * HH) * W2;
  size_t base = ((size_t)(b * 3) * (2 * HH) + 2 * y) * W2 + 2 * x;
  *(float2*)(out + base)              = make_float2(cp0, m1);
  *(float2*)(out + base + W2)         = make_float2(cp1, cp2);
  *(float2*)(out + base + plane)      = make_float2(m0, g0);
  *(float2*)(out + base + plane + W2) = make_float2(g1, m3);
  *(float2*)(out + base + 2 * plane)      = make_float2(cp3, cp4);
  *(float2*)(out + base + 2 * plane + W2) = make_float2(m2, cp5);
}

extern "C" void kernel_launch(void* const* d_in, const int* in_sizes, int n_in,
                              void* d_out, int out_size, void* d_ws, size_t ws_size,
                              hipStream_t stream) {
  const float* mosaic = (const float*)d_in[0];
  const float* fw0 = (const float*)d_in[1];
  const float* fw1 = (const float*)d_in[2];
  const float* fw2 = (const float*)d_in[3];
  const float* ww0 = (const float*)d_in[4];
  const float* ww1 = (const float*)d_in[5];
  const float* ww2 = (const float*)d_in[6];
  const float* cw0 = (const float*)d_in[7];

  uint4* wsf = (uint4*)((char*)d_ws + 32768);
  unsigned short* green = (unsigned short*)((char*)d_ws + 67584);
  float* out = (float*)d_out;

  wt_kernel<<<2, 256, 0, stream>>>(fw0, fw1, fw2, ww0, ww1, ww2, wsf);
  green_kernel<<<16 * 64 * 9, 256, 0, stream>>>(mosaic, wsf, green);
  assemble_kernel<<<(16 * HH * WW) / 256, 256, 0, stream>>>(mosaic, green, cw0, out);
}

// Round 12
// 193.719 us; speedup vs baseline: 1.5507x; 1.0458x over previous
//
#include <hip/hip_runtime.h>
#include <cstdint>

#define HH 512
#define WW 512
#define TX 58          // output tile width; 9 tiles cover 512 (last partial)
// grid = 16 * 64 * 9 = 9216 blocks

typedef __attribute__((ext_vector_type(8)))  short    short8;
typedef __attribute__((ext_vector_type(16))) float    f32x16;
typedef __attribute__((ext_vector_type(4)))  float    f32x4;
typedef __attribute__((ext_vector_type(2)))  unsigned u32x2;
typedef __attribute__((ext_vector_type(8)))  int      int8v;

union FragU { uint4 u; short8 s; };
union B8U   { u32x2 u2[2]; short8 s; };
union AF8   { uint4 u[2]; int8v v; };
union BF8   { unsigned d[8]; int8v v; };

// ---- LDS layout (bytes); fp8 act slot = 12B (ci0-3 @0, ci4-7 @4, ci8-11 @8) ----
// Row stride 832 B = 208 dw == 16 (mod 32): kg-group bases {0,16,0,16} dw ->
// scaled-B reads hit each bank exactly 2x (free). R10 strides (744/720) gave
// bases {0,26,20,..} -> 2.4e7 conflicts.
#define L1F_O  0        // 12 rows x 832B (62 px = 744B used, tail zeroed)
#define L1W_O  9984
#define L1RST  832
#define MOS_O  19968    // 14 rows x 64 px x 8B bf16 (dead after L1)
#define MOSR   512
#define L2F_O  19968    // aliases mosaic; 10 rows x 832B (60 px = 720B used, tail zeroed)
#define L2W_O  28288
#define L2RST  832
#define RELAY_O 0       // aliases dead L1 during L3; 4 waves x 64 slots x 52B = 13312
#define SMEMB  36608    // 4 blocks/CU

#define MFMA_SC(A, B, C) \
  __builtin_amdgcn_mfma_scale_f32_16x16x128_f8f6f4((A), (B), (C), 0, 0, 0, 0x7F7F7F7Fu, 0, 0x7F7F7F7Fu)

__device__ __forceinline__ unsigned cvtpk(float a, float b) {
  unsigned r;
  asm("v_cvt_pk_bf16_f32 %0, %1, %2" : "=v"(r) : "v"(a), "v"(b));
  return r;
}
__device__ __forceinline__ unsigned rpk8(float a, float b, float c, float d, bool im) {
  int r = __builtin_amdgcn_cvt_pk_fp8_f32(fmaxf(a, 0.f), fmaxf(b, 0.f), 0, false);
  r = __builtin_amdgcn_cvt_pk_fp8_f32(fmaxf(c, 0.f), fmaxf(d, 0.f), r, true);
  return im ? (unsigned)r : 0u;
}
__device__ __forceinline__ unsigned short f2bf(float f) {
  union { float f; unsigned u; } v; v.f = f;
  unsigned r = v.u + 0x7fffu + ((v.u >> 16) & 1u);
  return (unsigned short)(r >> 16);
}
__device__ __forceinline__ float bf2f(unsigned short b) {
  union { unsigned u; float f; } v; v.u = ((unsigned)b) << 16;
  return v.f;
}
__device__ __forceinline__ float lo16(unsigned u) {
  union { unsigned v; float f; } x; x.v = u << 16; return x.f;
}
__device__ __forceinline__ float hi16(unsigned u) {
  union { unsigned v; float f; } x; x.v = u & 0xffff0000u; return x.f;
}

// ---------------- weight packer (EXACT R10 mapping — HW-verified) ----------------
// t 0-191: L1 merged bf16 frags (f=t>>6=ky), rows 0-11 fw0, 12-23 ww0;
//          slot sq = 2h + e/4 -> kx = sq (sq==3 zero). 16B/lane.
// t 192-447: scaled K=128 frags, sid={L2F,L2W,L3F,L3W} at 192+sid*128+lane*2.
//   lane: m=lane&15 (co), kg=lane>>4.
//   kg<3 : byte e (0-31): dx=e/12, ci=e%12, tap=kg*3+dx.
//   kg==3: e=8i+j, valid i<3,j<4: tap=i*3+2, ci=8+j (row-tails); else 0.
// L3 W set pre-scaled 1/ln2 (softmax via exp2).
__global__ void wt_kernel(const float* __restrict__ fw0, const float* __restrict__ fw1,
                          const float* __restrict__ fw2, const float* __restrict__ ww0,
                          const float* __restrict__ ww1, const float* __restrict__ ww2,
                          uint4* __restrict__ wsf) {
  int t = blockIdx.x * 256 + threadIdx.x;
  if (t >= 448) return;
  if (t < 192) {
    int f = t >> 6, lane = t & 63;
    int h = (lane >> 5) & 1, m = lane & 31;
    unsigned short v[8];
#pragma unroll
    for (int e = 0; e < 8; ++e) {
      int sq = 2 * h + (e >> 2);
      int c4 = e & 3;
      float w = 0.f;
      if (sq < 3 && m < 24) {
        w = (m < 12) ? fw0[(m * 4 + c4) * 9 + f * 3 + sq]
                     : ww0[((m - 12) * 4 + c4) * 9 + f * 3 + sq];
      }
      v[e] = f2bf(w);
    }
    uint4 o;
    o.x = (unsigned)v[0] | ((unsigned)v[1] << 16);
    o.y = (unsigned)v[2] | ((unsigned)v[3] << 16);
    o.z = (unsigned)v[4] | ((unsigned)v[5] << 16);
    o.w = (unsigned)v[6] | ((unsigned)v[7] << 16);
    wsf[t] = o;
  } else {
    int u = t - 192, sid = u >> 6, lane = u & 63;
    int m = lane & 15, kg = lane >> 4;
    int layer = sid >> 1, path = sid & 1;
    const float* src = layer ? (path ? ww2 : fw2) : (path ? ww1 : fw1);
    const float scale = (layer == 1 && path == 1) ? 1.44269504f : 1.0f;
    unsigned d[8];
#pragma unroll
    for (int k = 0; k < 8; ++k) {
      float w4[4];
#pragma unroll
      for (int j4 = 0; j4 < 4; ++j4) {
        int e = 4 * k + j4;
        float w = 0.f;
        if (m < 12) {
          if (kg < 3) {
            int dx = e / 12, ci = e % 12, tap = kg * 3 + dx;
            w = src[(m * 12 + ci) * 9 + tap] * scale;
          } else {
            int i = e >> 3, j = e & 7;
            if (i < 3 && j < 4) {
              int tap = i * 3 + 2, ci = 8 + j;
              w = src[(m * 12 + ci) * 9 + tap] * scale;
            }
          }
        }
        w4[j4] = w;
      }
      int x = __builtin_amdgcn_cvt_pk_fp8_f32(w4[0], w4[1], 0, false);
      x = __builtin_amdgcn_cvt_pk_fp8_f32(w4[2], w4[3], x, true);
      d[k] = (unsigned)x;
    }
    uint4* dst = wsf + 192 + sid * 128 + lane * 2;
    dst[0] = make_uint4(d[0], d[1], d[2], d[3]);
    dst[1] = make_uint4(d[4], d[5], d[6], d[7]);
  }
}

// ---------------- fused 3-layer x 2-path conv (MX K=128 MFMA) + softmax green ----------------
__global__ __launch_bounds__(256, 4)
void green_kernel(const float* __restrict__ mosaic, const uint4* __restrict__ wsf,
                  unsigned short* __restrict__ green) {
  __shared__ __align__(16) char s[SMEMB];
  const int tid = threadIdx.x;
  const int lane = tid & 63;
  const int wv = __builtin_amdgcn_readfirstlane(tid >> 6);
  const int h = (lane >> 5) & 1, ln = lane & 31;
  const int ln8 = ln * 8, ln12 = ln * 12;
  const int pxl = lane & 15, kg = lane >> 4;
  const int bid = blockIdx.x;
  const int bx = bid % 9;
  const int t9 = bid / 9;
  const int by = t9 & 63, b = t9 >> 6;
  const int X0 = bx * TX, Y0 = by * 8;

  // ---- stage 0: mosaic tile 14x64 bf16 + zero L1 row tails (pad-read safety) ----
  {
    const float* mb = mosaic + (size_t)b * 4 * HH * WW;
    for (int p = tid; p < 14 * 64; p += 256) {
      int row = p >> 6, col = p & 63;
      int gy = Y0 + row - 3, gx = X0 + col - 3;
      float c0 = 0.f, c1 = 0.f, c2 = 0.f, c3 = 0.f;
      if ((unsigned)gy < HH && (unsigned)gx < WW) {
        const float* mp = mb + (size_t)gy * WW + gx;
        c0 = mp[0]; c1 = mp[HH * WW]; c2 = mp[2 * HH * WW]; c3 = mp[3 * HH * WW];
      }
      u32x2 w = { cvtpk(c0, c1), cvtpk(c2, c3) };
      *(u32x2*)(s + MOS_O + row * MOSR + col * 8) = w;
    }
    for (int i = tid; i < 528; i += 256) {   // 24 segs x 22 dw: L1F/L1W tails 744..832
      int seg = i / 22, d = i - seg * 22;
      int row = seg % 12, w = seg / 12;
      *(unsigned*)(s + w * 9984 + row * 832 + 744 + d * 4) = 0u;
    }
  }
  __syncthreads();

  // ---- L1: 4->12 both paths in one bf16 MFMA (M: F 0-11, W 12-23), out 12x62 fp8 ----
  {
    FragU a3[3];
#pragma unroll
    for (int q = 0; q < 3; ++q) a3[q].u = wsf[q * 64 + lane];
    const char* pLo = s + MOS_O + 3 * wv * MOSR + ln8 + 16 * h;
    const char* pHi = s + MOS_O + 3 * wv * MOSR + ln8 + 8;
    char* base = s + 3 * wv * L1RST + ln12;
    char* pA = base + L1F_O + 4 * h;
    char* pB = h ? base + L1W_O : base + L1F_O + 8;
    char* pC = base + L1W_O + (h ? 8 : 4);
    bool ck[2];
    ck[0] = (unsigned)(X0 + 0  + ln - 2) < WW;
    ck[1] = (unsigned)(X0 + 30 + ln - 2) < WW;
#pragma unroll
    for (int r = 0; r < 3; ++r) {
      const int ly = 3 * wv + r;
      const bool rowok = (unsigned)(Y0 + ly - 2) < HH;
#pragma unroll
      for (int g = 0; g < 2; ++g) {
        const int cb = g * 30;
        f32x16 c = {};
#pragma unroll
        for (int ky = 0; ky < 3; ++ky) {
          B8U bu;
          bu.u2[0] = *(const u32x2*)(pLo + (r + ky) * MOSR + cb * 8);
          bu.u2[1] = *(const u32x2*)(pHi + (r + ky) * MOSR + cb * 8);
          c = __builtin_amdgcn_mfma_f32_32x32x16_bf16(a3[ky].s, bu.s, c, 0, 0, 0);
        }
        const bool im = rowok && ck[g];
        *(unsigned*)(pA + r * L1RST + cb * 12) = rpk8(c[0], c[1], c[2], c[3], im);
        *(unsigned*)(pB + r * L1RST + cb * 12) = rpk8(c[4], c[5], c[6], c[7], im);
        *(unsigned*)(pC + r * L1RST + cb * 12) = rpk8(c[8], c[9], c[10], c[11], im);
      }
    }
  }
  __syncthreads();

  // ---- L2: 12->12 both chains, ONE scaled MFMA per 16px per chain, out 10x60 ----
  {
    // zero L2F/L2W row tails 720..832 (mosaic now dead; visible to L3 via next barrier)
    for (int i = tid; i < 560; i += 256) {   // 20 segs x 28 dw
      int seg = i / 28, d = i - seg * 28;
      int row = seg % 10, w = seg / 10;
      *(unsigned*)(s + L2F_O + w * 8320 + row * 832 + 720 + d * 4) = 0u;
    }
    AF8 aF, aW;
    aF.u[0] = wsf[192 + lane * 2]; aF.u[1] = wsf[193 + lane * 2];
    aW.u[0] = wsf[320 + lane * 2]; aW.u[1] = wsf[321 + lane * 2];
    const int c0 = (wv == 0) ? 0 : (wv == 1) ? 16 : (wv == 2) ? 32 : 44;
    int o0, o1, o2, o3;
    if (kg < 3) { o0 = kg * L1RST + pxl * 12; o1 = o0 + 8; o2 = o0 + 16; o3 = o0 + 24; }
    else        { o0 = (pxl + 2) * 12 + 8; o1 = o0 + L1RST; o2 = o1 + L1RST; o3 = o2; }
    const char* P0 = s + L1F_O + c0 * 12 + o0;
    const char* P1 = s + L1F_O + c0 * 12 + o1;
    const char* P2 = s + L1F_O + c0 * 12 + o2;
    const char* P3 = s + L1F_O + c0 * 12 + o3;
    const bool ckx = (unsigned)(X0 + c0 + pxl - 1) < WW;
    char* pO = s + L2F_O + (c0 + pxl) * 12 + 4 * kg;
#pragma unroll
    for (int ly = 0; ly < 10; ++ly) {
      const int imm = ly * L1RST;
      BF8 bF, bW;
      bF.d[0] = *(const unsigned*)(P0 + imm);        bF.d[1] = *(const unsigned*)(P0 + imm + 4);
      bF.d[2] = *(const unsigned*)(P1 + imm);        bF.d[3] = *(const unsigned*)(P1 + imm + 4);
      bF.d[4] = *(const unsigned*)(P2 + imm);        bF.d[5] = *(const unsigned*)(P2 + imm + 4);
      bF.d[6] = *(const unsigned*)(P3 + imm);        bF.d[7] = *(const unsigned*)(P3 + imm + 4);
      bW.d[0] = *(const unsigned*)(P0 + imm + 9984); bW.d[1] = *(const unsigned*)(P0 + imm + 9988);
      bW.d[2] = *(const unsigned*)(P1 + imm + 9984); bW.d[3] = *(const unsigned*)(P1 + imm + 9988);
      bW.d[4] = *(const unsigned*)(P2 + imm + 9984); bW.d[5] = *(const unsigned*)(P2 + imm + 9988);
      bW.d[6] = *(const unsigned*)(P3 + imm + 9984); bW.d[7] = *(const unsigned*)(P3 + imm + 9988);
      f32x4 cF = {0.f, 0.f, 0.f, 0.f}, cW = {0.f, 0.f, 0.f, 0.f};
      cF = MFMA_SC(aF.v, bF.v, cF);
      cW = MFMA_SC(aW.v, bW.v, cW);
      const bool im = ckx && ((unsigned)(Y0 + ly - 1) < HH);
      if (kg < 3) {
        *(unsigned*)(pO + ly * L2RST)        = rpk8(cF[0], cF[1], cF[2], cF[3], im);
        *(unsigned*)(pO + ly * L2RST + 8320) = rpk8(cW[0], cW[1], cW[2], cW[3], im);
      }
    }
  }
  __syncthreads();

  // ---- L3: scaled MFMA + relay (52B slots, bank-free reads) + softmax, out 8x58 ----
  {
    AF8 aF, aW;
    aF.u[0] = wsf[448 + lane * 2]; aF.u[1] = wsf[449 + lane * 2];
    aW.u[0] = wsf[576 + lane * 2]; aW.u[1] = wsf[577 + lane * 2];
    const int c0 = (wv == 0) ? 0 : (wv == 1) ? 16 : (wv == 2) ? 32 : 42;
    int o0, o1, o2, o3;
    if (kg < 3) { o0 = kg * L2RST + pxl * 12; o1 = o0 + 8; o2 = o0 + 16; o3 = o0 + 24; }
    else        { o0 = (pxl + 2) * 12 + 8; o1 = o0 + L2RST; o2 = o1 + L2RST; o3 = o2; }
    const char* P0 = s + L2F_O + c0 * 12 + o0;
    const char* P1 = s + L2F_O + c0 * 12 + o1;
    const char* P2 = s + L2F_O + c0 * 12 + o2;
    const char* P3 = s + L2F_O + c0 * 12 + o3;
    char* relay = s + RELAY_O + wv * 3328;
#pragma unroll
    for (int half = 0; half < 2; ++half) {
#pragma unroll
      for (int rr = 0; rr < 4; ++rr) {
        const int imm = (half * 4 + rr) * L2RST;
        BF8 bF, bW;
        bF.d[0] = *(const unsigned*)(P0 + imm);        bF.d[1] = *(const unsigned*)(P0 + imm + 4);
        bF.d[2] = *(const unsigned*)(P1 + imm);        bF.d[3] = *(const unsigned*)(P1 + imm + 4);
        bF.d[4] = *(const unsigned*)(P2 + imm);        bF.d[5] = *(const unsigned*)(P2 + imm + 4);
        bF.d[6] = *(const unsigned*)(P3 + imm);        bF.d[7] = *(const unsigned*)(P3 + imm + 4);
        bW.d[0] = *(const unsigned*)(P0 + imm + 8320); bW.d[1] = *(const unsigned*)(P0 + imm + 8324);
        bW.d[2] = *(const unsigned*)(P1 + imm + 8320); bW.d[3] = *(const unsigned*)(P1 + imm + 8324);
        bW.d[4] = *(const unsigned*)(P2 + imm + 8320); bW.d[5] = *(const unsigned*)(P2 + imm + 8324);
        bW.d[6] = *(const unsigned*)(P3 + imm + 8320); bW.d[7] = *(const unsigned*)(P3 + imm + 8324);
        f32x4 cF = {0.f, 0.f, 0.f, 0.f}, cW = {0.f, 0.f, 0.f, 0.f};
        cF = MFMA_SC(aF.v, bF.v, cF);
        cW = MFMA_SC(aW.v, bW.v, cW);
        if (kg < 3) {
          char* slot = relay + ((rr << 4) + pxl) * 52 + kg * 8;
          *(unsigned*)(slot)      = cvtpk(fmaxf(cF[0], 0.f), fmaxf(cF[1], 0.f));
          *(unsigned*)(slot + 4)  = cvtpk(fmaxf(cF[2], 0.f), fmaxf(cF[3], 0.f));
          *(unsigned*)(slot + 24) = cvtpk(fmaxf(cW[0], 0.f), fmaxf(cW[1], 0.f));
          *(unsigned*)(slot + 28) = cvtpk(fmaxf(cW[2], 0.f), fmaxf(cW[3], 0.f));
        }
      }
      asm volatile("s_waitcnt lgkmcnt(0)" ::: "memory");
      {
        const char* slot = relay + lane * 52;
        unsigned fu[6], wu[6];
#pragma unroll
        for (int i = 0; i < 6; ++i) {
          fu[i] = *(const unsigned*)(slot + i * 4);
          wu[i] = *(const unsigned*)(slot + 24 + i * 4);
        }
        float F[12], Wv[12];
#pragma unroll
        for (int i = 0; i < 6; ++i) {
          F[2 * i] = lo16(fu[i]);  F[2 * i + 1] = hi16(fu[i]);
          Wv[2 * i] = lo16(wu[i]); Wv[2 * i + 1] = hi16(wu[i]);
        }
        float m = 0.f;
#pragma unroll
        for (int c2 = 0; c2 < 12; ++c2) m = fmaxf(m, Wv[c2]);
        float sum = 0.f, s0 = 0.f, s1 = 0.f;
#pragma unroll
        for (int c2 = 0; c2 < 12; ++c2) {
          const float e = exp2f(Wv[c2] - m);   // W logits pre-scaled by 1/ln2
          sum += e;
          if (c2 < 6) s0 = fmaf(F[c2], e, s0);
          else        s1 = fmaf(F[c2], e, s1);
        }
        const float inv = 1.f / sum;
        const unsigned pg = cvtpk(s0 * inv, s1 * inv);
        const int gy = Y0 + half * 4 + kg;
        const int gx = X0 + c0 + pxl;
        if ((unsigned)gx < WW) {
          green[((b * 2 + 0) * HH + gy) * WW + gx] = (unsigned short)pg;
          green[((b * 2 + 1) * HH + gy) * WW + gx] = (unsigned short)(pg >> 16);
        }
      }
      asm volatile("s_waitcnt lgkmcnt(0)" ::: "memory");
    }
  }
}

// ---------------- chroma conv 2->6 + pixel-shuffle assembly ----------------
__global__ __launch_bounds__(256)
void assemble_kernel(const float* __restrict__ mosaic, const unsigned short* __restrict__ green,
                     const float* __restrict__ cw0, float* __restrict__ out) {
  const int t = blockIdx.x * 256 + threadIdx.x;
  const int x = t & (WW - 1);
  const int y = (t >> 9) & (HH - 1);
  const int b = t >> 18;

  const int p = y * WW + x;
  const float* __restrict__ mb = mosaic + (size_t)b * 4 * HH * WW;
  const unsigned short* __restrict__ gb = green + (size_t)b * 2 * HH * WW;

  const float m0 = mb[p];
  const float m1 = mb[HH * WW + p];
  const float m2 = mb[2 * HH * WW + p];
  const float m3 = mb[3 * HH * WW + p];
  const float g0 = bf2f(gb[p]);
  const float g1 = bf2f(gb[HH * WW + p]);

  float cd[6] = {0.f, 0.f, 0.f, 0.f, 0.f, 0.f};
#pragma unroll
  for (int ky = 0; ky < 3; ++ky) {
#pragma unroll
    for (int kx = 0; kx < 3; ++kx) {
      const int yy = y + ky - 1, xx = x + kx - 1;
      float c0 = 0.f, c1 = 0.f;
      if ((unsigned)yy < HH && (unsigned)xx < WW) {
        const int q = yy * WW + xx;
        c0 = mb[HH * WW + q]     - bf2f(gb[q]);
        c1 = mb[2 * HH * WW + q] - bf2f(gb[HH * WW + q]);
      }
      const int k = ky * 3 + kx;
#pragma unroll
      for (int o = 0; o < 6; ++o) {
        cd[o] = fmaf(c0, cw0[(o * 2 + 0) * 9 + k], cd[o]);
        cd[o] = fmaf(c1, cw0[(o * 2 + 1) * 9 + k], cd[o]);
      }
    }
  }
  const float cp0 = cd[0] + m0;
  const float cp1 = cd[1] + g1;
  const float cp2 = cd[2] + m3;
  const float cp3 = cd[3] + m0;
  const float cp4 = cd[4] + g0;
  const float cp5 = cd[5] + m3;

  const int W2 = 2 * WW;
  const size_t plane = (size_t)(2 * HH) * W2;
  size_t base = ((size_t)(b * 3) * (2 * HH) + 2 * y) * W2 + 2 * x;
  *(float2*)(out + base)              = make_float2(cp0, m1);
  *(float2*)(out + base + W2)         = make_float2(cp1, cp2);
  *(float2*)(out + base + plane)      = make_float2(m0, g0);
  *(float2*)(out + base + plane + W2) = make_float2(g1, m3);
  *(float2*)(out + base + 2 * plane)      = make_float2(cp3, cp4);
  *(float2*)(out + base + 2 * plane + W2) = make_float2(m2, cp5);
}

extern "C" void kernel_launch(void* const* d_in, const int* in_sizes, int n_in,
                              void* d_out, int out_size, void* d_ws, size_t ws_size,
                              hipStream_t stream) {
  const float* mosaic = (const float*)d_in[0];
  const float* fw0 = (const float*)d_in[1];
  const float* fw1 = (const float*)d_in[2];
  const float* fw2 = (const float*)d_in[3];
  const float* ww0 = (const float*)d_in[4];
  const float* ww1 = (const float*)d_in[5];
  const float* ww2 = (const float*)d_in[6];
  const float* cw0 = (const float*)d_in[7];

  uint4* wsf = (uint4*)((char*)d_ws + 32768);
  unsigned short* green = (unsigned short*)((char*)d_ws + 67584);
  float* out = (float*)d_out;

  wt_kernel<<<2, 256, 0, stream>>>(fw0, fw1, fw2, ww0, ww1, ww2, wsf);
  green_kernel<<<16 * 64 * 9, 256, 0, stream>>>(mosaic, wsf, green);
  assemble_kernel<<<(16 * HH * WW) / 256, 256, 0, stream>>>(mosaic, green, cw0, out);
}